// Round 15
// baseline (88.477 us; speedup 1.0000x reference)
//
#include <hip/hip_runtime.h>
#include <hip/hip_bf16.h>

typedef __attribute__((ext_vector_type(4))) float f32x4;
typedef __attribute__((ext_vector_type(16))) float f32x16;
typedef __attribute__((ext_vector_type(8))) short short8;
typedef __attribute__((ext_vector_type(4))) int i32x4;

#define S_LEN 4096
#define DM    1024
#define NH    16
#define DH    64
#define WIN   256

__device__ inline unsigned short f2b(float f) {
  unsigned int x = __float_as_uint(f);
  unsigned int r = (x + 0x7fffu + ((x >> 16) & 1u)) >> 16;
  return (unsigned short)r;
}

__device__ inline void gload_lds16(const void* g, void* l) {
  __builtin_amdgcn_global_load_lds(
      (const __attribute__((address_space(1))) void*)g,
      (__attribute__((address_space(3))) void*)l, 16, 0, 0);
}

// ---------------------------------------------------------------------------
// Convert X and the 4 weight matrices f32 -> bf16.
// ---------------------------------------------------------------------------
__global__ __launch_bounds__(256) void cvt_all(
    const float* __restrict__ x,
    const float* __restrict__ qw, const float* __restrict__ kw,
    const float* __restrict__ vw, const float* __restrict__ ow,
    unsigned short* __restrict__ Xb, unsigned short* __restrict__ Wb)
{
  const int y = blockIdx.y;
  const float* src;
  unsigned short* dst;
  int n8;
  if (y == 0) { src = x; dst = Xb; n8 = (S_LEN * DM) / 8; }
  else {
    src = (y == 1) ? qw : (y == 2) ? kw : (y == 3) ? vw : ow;
    dst = Wb + (size_t)(y - 1) * DM * DM;
    n8 = (DM * DM) / 8;
  }
  const int i = blockIdx.x * 256 + threadIdx.x;
  if (i >= n8) return;
  const float4* s4 = (const float4*)src + (size_t)i * 2;
  float4 a = s4[0], b = s4[1];
  short8 v;
  v[0] = f2b(a.x); v[1] = f2b(a.y); v[2] = f2b(a.z); v[3] = f2b(a.w);
  v[4] = f2b(b.x); v[5] = f2b(b.y); v[6] = f2b(b.z); v[7] = f2b(b.w);
  *(short8*)(dst + (size_t)i * 8) = v;
}

#define PIPE_WAIT8  asm volatile("s_waitcnt vmcnt(8)" ::: "memory")
#define PIPE_WAIT7  asm volatile("s_waitcnt vmcnt(7)" ::: "memory")
#define PIPE_WAIT0  asm volatile("s_waitcnt vmcnt(0)" ::: "memory")
#define PIPE_BAR    do { __builtin_amdgcn_s_barrier(); __builtin_amdgcn_sched_barrier(0); } while (0)
#define PIPE_ENDBAR do { __builtin_amdgcn_sched_barrier(0); __builtin_amdgcn_s_barrier(); \
                         __builtin_amdgcn_sched_barrier(0); } while (0)

// ---------------------------------------------------------------------------
// Fused QKV GEMM (4096x3072), BM=256 BN=192, grid 16x16 = 256 blocks = 1/CU,
// 2-phase counted-vmcnt pipeline (round-10 measured-best form, no swizzle).
// ---------------------------------------------------------------------------
__global__ __launch_bounds__(512, 1) void gemm_qkv_fused(
    const unsigned short* __restrict__ A,    // Xb [4096][1024]
    const unsigned short* __restrict__ W,    // Wcv rows 0..3071 = q,k,v
    const float* __restrict__ bq, const float* __restrict__ bk, const float* __restrict__ bv,
    unsigned short* __restrict__ Qb)         // K at +SD, V at +2SD
{
  constexpr int BM = 256, BN = 192;
  constexpr int REGA = BM * 64;
  constexpr int BUF = REGA + BN * 64;
  __shared__ __align__(16) unsigned short LDS[2 * BUF];
  unsigned short* A0 = LDS;
  unsigned short* B0 = LDS + REGA;
  unsigned short* A1 = LDS + BUF;
  unsigned short* B1 = LDS + BUF + REGA;

  const int t = threadIdx.x;
  const int lane = t & 63, w = t >> 6;
  const int wm = w >> 2, wn = w & 3;
  const int lr = lane & 15, lg = lane >> 4;
  const int m0 = blockIdx.x * BM, n0 = blockIdx.y * BN;

  int sr[4], sc[4], sb[4];
#pragma unroll
  for (int i = 0; i < 4; ++i) {
    const int bo = (i * 512 + w * 64) * 16;
    const int o = bo + lane * 16;
    const int row = o >> 7, colb = o & 127;
    const int colp = colb ^ ((row & 3) << 4) ^ (((row >> 2) & 1) << 6);
    sr[i] = row; sc[i] = colp >> 1; sb[i] = bo >> 1;
  }

#define STAGE(e0, lA, lB)                                                           \
  do {                                                                              \
    _Pragma("unroll") for (int i = 0; i < 4; ++i)                                   \
      gload_lds16(A + (size_t)(m0 + sr[i]) * DM + (e0) + sc[i], (lA) + sb[i]);      \
    _Pragma("unroll") for (int i = 0; i < 3; ++i)                                   \
      gload_lds16(W + (size_t)(n0 + sr[i]) * DM + (e0) + sc[i], (lB) + sb[i]);      \
  } while (0)

  f32x4 acc[8][3];
#pragma unroll
  for (int m = 0; m < 8; ++m)
#pragma unroll
    for (int n = 0; n < 3; ++n) acc[m][n] = (f32x4){0.f, 0.f, 0.f, 0.f};

  const int xor6l = ((lr >> 2) & 1) << 6;
  const int xor45 = (lg << 4) ^ ((lr & 3) << 4);

#define COMPUTE(sAp, sBp)                                                           \
  do {                                                                              \
    _Pragma("unroll") for (int kk = 0; kk < 2; ++kk) {                              \
      const int coff = ((kk << 6) ^ xor6l) + xor45;                                 \
      short8 af[8], bf[3];                                                          \
      _Pragma("unroll") for (int m = 0; m < 8; ++m)                                 \
        af[m] = *(const short8*)((const char*)(sAp) + (wm * 128 + m * 16 + lr) * 128 + coff); \
      _Pragma("unroll") for (int n = 0; n < 3; ++n)                                 \
        bf[n] = *(const short8*)((const char*)(sBp) + (wn * 48 + n * 16 + lr) * 128 + coff); \
      _Pragma("unroll") for (int m = 0; m < 8; ++m)                                 \
        _Pragma("unroll") for (int n = 0; n < 3; ++n)                               \
          acc[m][n] = __builtin_amdgcn_mfma_f32_16x16x32_bf16(af[m], bf[n], acc[m][n], 0, 0, 0); \
    }                                                                               \
  } while (0)

  STAGE(0, A0, B0);
#pragma unroll 1
  for (int kt = 0; kt < 14; kt += 2) {
    STAGE((kt + 1) * 64, A1, B1);
    PIPE_WAIT7; PIPE_BAR;
    __builtin_amdgcn_s_setprio(1);
    COMPUTE(A0, B0);
    __builtin_amdgcn_s_setprio(0);
    PIPE_ENDBAR;
    STAGE((kt + 2) * 64, A0, B0);
    PIPE_WAIT7; PIPE_BAR;
    __builtin_amdgcn_s_setprio(1);
    COMPUTE(A1, B1);
    __builtin_amdgcn_s_setprio(0);
    PIPE_ENDBAR;
  }
  STAGE(15 * 64, A1, B1);
  PIPE_WAIT7; PIPE_BAR;
  __builtin_amdgcn_s_setprio(1);
  COMPUTE(A0, B0);
  __builtin_amdgcn_s_setprio(0);
  PIPE_ENDBAR;
  PIPE_WAIT0; PIPE_BAR;
  __builtin_amdgcn_s_setprio(1);
  COMPUTE(A1, B1);
  __builtin_amdgcn_s_setprio(0);

#undef STAGE
#undef COMPUTE

#pragma unroll
  for (int n = 0; n < 3; ++n) {
    const int gc = n0 + wn * 48 + n * 16 + lr;
    const int slice = gc >> 10, col = gc & 1023;
    const float* bp = (slice == 0) ? bq : (slice == 1) ? bk : bv;
    const float bv_ = bp[col];
    unsigned short* Obase = Qb + (size_t)slice * ((size_t)S_LEN * DM);
#pragma unroll
    for (int m = 0; m < 8; ++m) {
      const int gr0 = m0 + wm * 128 + m * 16 + lg * 4;
#pragma unroll
      for (int r = 0; r < 4; ++r)
        Obase[(size_t)(gr0 + r) * DM + col] = f2b(acc[m][n][r] + bv_);
    }
  }
}

// ---------------------------------------------------------------------------
// 128x128 2-phase pipelined GEMM for the output projection (round-10 form).
// ---------------------------------------------------------------------------
__global__ __launch_bounds__(256, 1) void gemm_out(
    const unsigned short* __restrict__ A,
    const unsigned short* __restrict__ Bmat,
    const float* __restrict__ bias,
    float* __restrict__ Of)
{
  constexpr int REG = 128 * 64;
  __shared__ __align__(16) unsigned short LDS[4 * REG];
  unsigned short* A0 = LDS;
  unsigned short* A1 = LDS + REG;
  unsigned short* B0 = LDS + 2 * REG;
  unsigned short* B1 = LDS + 3 * REG;

  const int t = threadIdx.x;
  const int lane = t & 63, w = t >> 6;
  const int wm = w >> 1, wn = w & 1;
  const int lr = lane & 15, lg = lane >> 4;
  const int m0 = blockIdx.x * 128, n0 = blockIdx.y * 128;

  int sr[4], sc[4], sb[4];
#pragma unroll
  for (int i = 0; i < 4; ++i) {
    const int bo = (i * 256 + w * 64) * 16;
    const int o = bo + lane * 16;
    const int row = o >> 7, colb = o & 127;
    const int colp = colb ^ ((row & 3) << 4) ^ (((row >> 2) & 1) << 6);
    sr[i] = row; sc[i] = colp >> 1; sb[i] = bo >> 1;
  }

#define STAGE(e0, lA, lB)                                                           \
  do {                                                                              \
    _Pragma("unroll") for (int i = 0; i < 4; ++i) {                                 \
      gload_lds16(A + (size_t)(m0 + sr[i]) * DM + (e0) + sc[i], (lA) + sb[i]);      \
      gload_lds16(Bmat + (size_t)(n0 + sr[i]) * DM + (e0) + sc[i], (lB) + sb[i]);   \
    }                                                                               \
  } while (0)

  f32x4 acc[4][4];
#pragma unroll
  for (int m = 0; m < 4; ++m)
#pragma unroll
    for (int n = 0; n < 4; ++n) acc[m][n] = (f32x4){0.f, 0.f, 0.f, 0.f};

  const int xor6l = ((lr >> 2) & 1) << 6;
  const int xor45 = (lg << 4) ^ ((lr & 3) << 4);

#define COMPUTE(sAp, sBp)                                                           \
  do {                                                                              \
    _Pragma("unroll") for (int kk = 0; kk < 2; ++kk) {                              \
      const int coff = ((kk << 6) ^ xor6l) + xor45;                                 \
      short8 af[4], bf[4];                                                          \
      _Pragma("unroll") for (int m = 0; m < 4; ++m)                                 \
        af[m] = *(const short8*)((const char*)(sAp) + (wm * 64 + m * 16 + lr) * 128 + coff); \
      _Pragma("unroll") for (int n = 0; n < 4; ++n)                                 \
        bf[n] = *(const short8*)((const char*)(sBp) + (wn * 64 + n * 16 + lr) * 128 + coff); \
      _Pragma("unroll") for (int m = 0; m < 4; ++m)                                 \
        _Pragma("unroll") for (int n = 0; n < 4; ++n)                               \
          acc[m][n] = __builtin_amdgcn_mfma_f32_16x16x32_bf16(af[m], bf[n], acc[m][n], 0, 0, 0); \
    }                                                                               \
  } while (0)

  STAGE(0, A0, B0);
#pragma unroll 1
  for (int kt = 0; kt < 14; kt += 2) {
    STAGE((kt + 1) * 64, A1, B1);
    PIPE_WAIT8; PIPE_BAR;
    __builtin_amdgcn_s_setprio(1);
    COMPUTE(A0, B0);
    __builtin_amdgcn_s_setprio(0);
    PIPE_ENDBAR;
    STAGE((kt + 2) * 64, A0, B0);
    PIPE_WAIT8; PIPE_BAR;
    __builtin_amdgcn_s_setprio(1);
    COMPUTE(A1, B1);
    __builtin_amdgcn_s_setprio(0);
    PIPE_ENDBAR;
  }
  STAGE(15 * 64, A1, B1);
  PIPE_WAIT8; PIPE_BAR;
  __builtin_amdgcn_s_setprio(1);
  COMPUTE(A0, B0);
  __builtin_amdgcn_s_setprio(0);
  PIPE_ENDBAR;
  PIPE_WAIT0; PIPE_BAR;
  __builtin_amdgcn_s_setprio(1);
  COMPUTE(A1, B1);
  __builtin_amdgcn_s_setprio(0);

#undef STAGE
#undef COMPUTE

#pragma unroll
  for (int n = 0; n < 4; ++n) {
    const int gc = n0 + wn * 64 + n * 16 + lr;
    const float bv = bias[gc];
#pragma unroll
    for (int m = 0; m < 4; ++m) {
      const int gr0 = m0 + wm * 64 + m * 16 + lg * 4;
#pragma unroll
      for (int r = 0; r < 4; ++r)
        Of[(size_t)(gr0 + r) * DM + gc] = acc[m][n][r] + bv;
    }
  }
}

// ---------------------------------------------------------------------------
// Sliding-window attention v4: K now staged through per-warp double-buffered
// LDS with COALESCED global loads (4x dwordx4 = 8 full 128B rows each; was
// 128 strided line-transactions per chunk) + XOR swizzle byte^=(row&7)<<4
// on write and read (m214-verified pattern).  V path and all softmax/PV
// math unchanged from the proven v2.
// ---------------------------------------------------------------------------
__global__ __launch_bounds__(256) void attn(
    const unsigned short* __restrict__ Q,
    const unsigned short* __restrict__ Km,
    const unsigned short* __restrict__ Vm,
    unsigned short* __restrict__ AO)
{
  const int warp = threadIdx.x >> 6;
  const int l = threadIdx.x & 63;
  const int qw0 = (blockIdx.x * 4 + warp) * 32;
  const int hD = blockIdx.y * DH;
  const int q = l & 31;
  const int hi = l >> 5;
  const int l31 = l & 31;
  const int vkey = (l & 15) * 2;
  const int vd0 = (l >> 4) * 16;
  const int krow8 = l >> 3;            // 0..7 (staging row within 8-row group)
  const int kcolb = (l & 7) * 16;      // staging byte-col 0..112
  const int kswz = kcolb ^ (krow8 << 4);
  const int rswz = (l31 & 7) << 4;     // read-side XOR for this lane's row

  __shared__ __align__(16) unsigned short VtS[4][2][64 * 40];
  __shared__ __align__(16) unsigned short KlS[4][2][32 * 64];
  unsigned short* vt0 = &VtS[warp][0][0];
  unsigned short* vt1 = &VtS[warp][1][0];
  char* kl0 = (char*)&KlS[warp][0][0];
  char* kl1 = (char*)&KlS[warp][1][0];

  short8 qf[4];
  {
    const unsigned short* qp = Q + (size_t)(qw0 + q) * DM + hD + hi * 8;
#pragma unroll
    for (int ks = 0; ks < 4; ++ks) qf[ks] = *(const short8*)(qp + ks * 16);
  }

  f32x16 o0{}, o1{};
  float lsum = 0.f;

  const int kb0 = (qw0 >= WIN) ? (qw0 - WIN) : 0;
  const int nch = (qw0 + 32 - kb0) >> 5;

  uint4 kr[4];
  short8 vfA[4], vfB[4];

#define KLOAD(kb_)                                                               \
  do {                                                                           \
    _Pragma("unroll") for (int i = 0; i < 4; ++i)                                \
      kr[i] = *(const uint4*)(Km + (size_t)((kb_) + i * 8 + krow8) * DM + hD + (kcolb >> 1)); \
  } while (0)

#define KWRITE(kl_)                                                              \
  do {                                                                           \
    _Pragma("unroll") for (int i = 0; i < 4; ++i)                                \
      *(uint4*)((kl_) + (i * 8 + krow8) * 128 + kswz) = kr[i];                   \
  } while (0)

#define LOADV(kb_, vf_)                                                          \
  do {                                                                           \
    const unsigned short* vp_ = Vm + (size_t)((kb_) + vkey) * DM + hD + vd0;     \
    (vf_)[0] = *(const short8*)vp_;                                              \
    (vf_)[1] = *(const short8*)(vp_ + 8);                                        \
    (vf_)[2] = *(const short8*)(vp_ + DM);                                       \
    (vf_)[3] = *(const short8*)(vp_ + DM + 8);                                   \
  } while (0)

#define PROCESS(kb_, kl_, vf_, vt_)                                             \
  do {                                                                          \
    const int kbv = (kb_);                                                      \
    _Pragma("unroll") for (int j = 0; j < 16; ++j) {                            \
      unsigned int wv = (unsigned int)(unsigned short)(vf_)[j >> 3][j & 7]      \
          | ((unsigned int)(unsigned short)(vf_)[2 + (j >> 3)][j & 7] << 16);   \
      *(unsigned int*)((vt_) + (vd0 + j) * 40 + vkey) = wv;                     \
    }                                                                           \
    short8 kf_[4];                                                              \
    _Pragma("unroll") for (int ks = 0; ks < 4; ++ks)                            \
      kf_[ks] = *(const short8*)((kl_) + l31 * 128 + ((ks * 32 + hi * 16) ^ rswz)); \
    f32x16 s{};                                                                 \
    _Pragma("unroll") for (int ks = 0; ks < 4; ++ks)                            \
      s = __builtin_amdgcn_mfma_f32_32x32x16_bf16(kf_[ks], qf[ks], s, 0, 0, 0); \
    float p[16];                                                                \
    const bool isEdge = (kbv >= qw0) || (kbv + WIN - 32 < qw0);                 \
    if (isEdge) {                                                               \
      _Pragma("unroll") for (int r = 0; r < 16; ++r) {                          \
        const int key = kbv + (r & 3) + 8 * (r >> 2) + 4 * hi;                  \
        const int qg = qw0 + q;                                                 \
        const bool valid = (key <= qg) && (qg - key < WIN);                     \
        p[r] = valid ? __expf(s[r] * 0.125f) : 0.f;                             \
        lsum += p[r];                                                           \
      }                                                                         \
    } else {                                                                    \
      _Pragma("unroll") for (int r = 0; r < 16; ++r) {                          \
        p[r] = __expf(s[r] * 0.125f);                                           \
        lsum += p[r];                                                           \
      }                                                                         \
    }                                                                           \
    unsigned int u[8];                                                          \
    _Pragma("unroll") for (int t2 = 0; t2 < 4; ++t2) {                          \
      __hip_bfloat162 h0_ = __float22bfloat162_rn(make_float2(p[4 * t2], p[4 * t2 + 1])); \
      __hip_bfloat162 h1_ = __float22bfloat162_rn(make_float2(p[4 * t2 + 2], p[4 * t2 + 3])); \
      u[2 * t2]     = *(unsigned int*)&h0_;                                     \
      u[2 * t2 + 1] = *(unsigned int*)&h1_;                                     \
    }                                                                           \
    const unsigned int sd0 = hi ? u[0] : u[2], sd1 = hi ? u[1] : u[3];          \
    const unsigned int rc0 = __shfl_xor(sd0, 32, 64), rc1 = __shfl_xor(sd1, 32, 64); \
    const unsigned int sd2 = hi ? u[4] : u[6], sd3 = hi ? u[5] : u[7];          \
    const unsigned int rc2 = __shfl_xor(sd2, 32, 64), rc3 = __shfl_xor(sd3, 32, 64); \
    i32x4 pw0, pw1;                                                             \
    pw0[0] = hi ? rc0 : u[0]; pw0[1] = hi ? rc1 : u[1];                         \
    pw0[2] = hi ? u[2] : rc0; pw0[3] = hi ? u[3] : rc1;                         \
    pw1[0] = hi ? rc2 : u[4]; pw1[1] = hi ? rc3 : u[5];                         \
    pw1[2] = hi ? u[6] : rc2; pw1[3] = hi ? u[7] : rc3;                         \
    const short8 pf0 = *(const short8*)&pw0;                                    \
    const short8 pf1 = *(const short8*)&pw1;                                    \
    const short8 a00 = *(const short8*)((vt_) + l31 * 40 + hi * 8);             \
    const short8 a01 = *(const short8*)((vt_) + l31 * 40 + 16 + hi * 8);        \
    const short8 a10 = *(const short8*)((vt_) + (32 + l31) * 40 + hi * 8);      \
    const short8 a11 = *(const short8*)((vt_) + (32 + l31) * 40 + 16 + hi * 8); \
    o0 = __builtin_amdgcn_mfma_f32_32x32x16_bf16(a00, pf0, o0, 0, 0, 0);        \
    o0 = __builtin_amdgcn_mfma_f32_32x32x16_bf16(a01, pf1, o0, 0, 0, 0);        \
    o1 = __builtin_amdgcn_mfma_f32_32x32x16_bf16(a10, pf0, o1, 0, 0, 0);        \
    o1 = __builtin_amdgcn_mfma_f32_32x32x16_bf16(a11, pf1, o1, 0, 0, 0);        \
  } while (0)

  // prologue: stage chunk 0
  KLOAD(kb0);
  LOADV(kb0, vfA);
  KWRITE(kl0);
  int c = 0;
#pragma unroll 1
  for (; c + 2 <= nch; c += 2) {
    const int kb = kb0 + c * 32;
    KLOAD(kb + 32);                 // issue-early: c+1 K loads
    LOADV(kb + 32, vfB);
    PROCESS(kb, kl0, vfA, vt0);     // compute chunk c (reads kl0)
    KWRITE(kl1);                    // write-late: c+1 K -> kl1
    if (c + 2 < nch) { KLOAD(kb + 64); LOADV(kb + 64, vfA); }
    PROCESS(kb + 32, kl1, vfB, vt1);
    if (c + 2 < nch) KWRITE(kl0);
  }
  if (c < nch) PROCESS(kb0 + c * 32, kl0, vfA, vt0);

#undef KLOAD
#undef KWRITE
#undef LOADV
#undef PROCESS

  lsum += __shfl_xor(lsum, 32, 64);
  const float inv = 1.f / lsum;
  unsigned short* aop = AO + (size_t)(qw0 + q) * DM + hD;
#pragma unroll
  for (int t2 = 0; t2 < 4; ++t2) {
    __hip_bfloat162 s0 = __float22bfloat162_rn(make_float2(o0[4*t2] * inv, o0[4*t2+1] * inv));
    __hip_bfloat162 s1 = __float22bfloat162_rn(make_float2(o0[4*t2+2] * inv, o0[4*t2+3] * inv));
    uint2 st; st.x = *(unsigned int*)&s0; st.y = *(unsigned int*)&s1;
    *(uint2*)(aop + 8 * t2 + 4 * hi) = st;
    __hip_bfloat162 s2 = __float22bfloat162_rn(make_float2(o1[4*t2] * inv, o1[4*t2+1] * inv));
    __hip_bfloat162 s3 = __float22bfloat162_rn(make_float2(o1[4*t2+2] * inv, o1[4*t2+3] * inv));
    uint2 st2; st2.x = *(unsigned int*)&s2; st2.y = *(unsigned int*)&s3;
    *(uint2*)(aop + 32 + 8 * t2 + 4 * hi) = st2;
  }
}

// ---------------------------------------------------------------------------
extern "C" void kernel_launch(void* const* d_in, const int* in_sizes, int n_in,
                              void* d_out, int out_size, void* d_ws, size_t ws_size,
                              hipStream_t stream) {
  const float* x  = (const float*)d_in[0];
  const float* qw = (const float*)d_in[1];
  const float* qb = (const float*)d_in[2];
  const float* kw = (const float*)d_in[3];
  const float* kb = (const float*)d_in[4];
  const float* vw = (const float*)d_in[5];
  const float* vb = (const float*)d_in[6];
  const float* ow = (const float*)d_in[7];
  const float* ob = (const float*)d_in[8];

  const size_t SD = (size_t)S_LEN * DM;
  unsigned short* Qb  = (unsigned short*)d_ws;
  unsigned short* Kb  = Qb + SD;
  unsigned short* Vb  = Kb + SD;
  unsigned short* AOb = Vb + SD;
  unsigned short* Xb  = AOb + SD;
  unsigned short* Wcv = Xb + SD;

  cvt_all<<<dim3(2048, 5), 256, 0, stream>>>(x, qw, kw, vw, ow, Xb, Wcv);
  gemm_qkv_fused<<<dim3(16, 16), 512, 0, stream>>>(Xb, Wcv, qb, kb, vb, Qb);
  attn<<<dim3(S_LEN / 128, NH), 256, 0, stream>>>(Qb, Kb, Vb, AOb);
  gemm_out<<<dim3(32, 8), 256, 0, stream>>>(AOb, Wcv + (size_t)3 * DM * DM, ob, (float*)d_out);
}

// Round 17
// 81.857 us; speedup vs baseline: 1.0809x; 1.0809x over previous
//
#include <hip/hip_runtime.h>
#include <hip/hip_bf16.h>

typedef __attribute__((ext_vector_type(4))) float f32x4;
typedef __attribute__((ext_vector_type(16))) float f32x16;
typedef __attribute__((ext_vector_type(8))) short short8;
typedef __attribute__((ext_vector_type(4))) int i32x4;

#define S_LEN 4096
#define DM    1024
#define NH    16
#define DH    64
#define WIN   256

__device__ inline unsigned short f2b(float f) {
  unsigned int x = __float_as_uint(f);
  unsigned int r = (x + 0x7fffu + ((x >> 16) & 1u)) >> 16;
  return (unsigned short)r;
}

__device__ inline void gload_lds16(const void* g, void* l) {
  __builtin_amdgcn_global_load_lds(
      (const __attribute__((address_space(1))) void*)g,
      (__attribute__((address_space(3))) void*)l, 16, 0, 0);
}

// ---------------------------------------------------------------------------
// Convert X and the 4 weight matrices f32 -> bf16.
// ---------------------------------------------------------------------------
__global__ __launch_bounds__(256) void cvt_all(
    const float* __restrict__ x,
    const float* __restrict__ qw, const float* __restrict__ kw,
    const float* __restrict__ vw, const float* __restrict__ ow,
    unsigned short* __restrict__ Xb, unsigned short* __restrict__ Wb)
{
  const int y = blockIdx.y;
  const float* src;
  unsigned short* dst;
  int n8;
  if (y == 0) { src = x; dst = Xb; n8 = (S_LEN * DM) / 8; }
  else {
    src = (y == 1) ? qw : (y == 2) ? kw : (y == 3) ? vw : ow;
    dst = Wb + (size_t)(y - 1) * DM * DM;
    n8 = (DM * DM) / 8;
  }
  const int i = blockIdx.x * 256 + threadIdx.x;
  if (i >= n8) return;
  const float4* s4 = (const float4*)src + (size_t)i * 2;
  float4 a = s4[0], b = s4[1];
  short8 v;
  v[0] = f2b(a.x); v[1] = f2b(a.y); v[2] = f2b(a.z); v[3] = f2b(a.w);
  v[4] = f2b(b.x); v[5] = f2b(b.y); v[6] = f2b(b.z); v[7] = f2b(b.w);
  *(short8*)(dst + (size_t)i * 8) = v;
}

#define PIPE_WAIT8  asm volatile("s_waitcnt vmcnt(8)" ::: "memory")
#define PIPE_WAIT7  asm volatile("s_waitcnt vmcnt(7)" ::: "memory")
#define PIPE_WAIT0  asm volatile("s_waitcnt vmcnt(0)" ::: "memory")
#define PIPE_BAR    do { __builtin_amdgcn_s_barrier(); __builtin_amdgcn_sched_barrier(0); } while (0)
#define PIPE_ENDBAR do { __builtin_amdgcn_sched_barrier(0); __builtin_amdgcn_s_barrier(); \
                         __builtin_amdgcn_sched_barrier(0); } while (0)

// ---------------------------------------------------------------------------
// Fused QKV GEMM (4096x3072), BM=256 BN=192, grid 16x16 = 256 blocks = 1/CU,
// 2-phase counted-vmcnt pipeline (round-10 measured-best form).
// ---------------------------------------------------------------------------
__global__ __launch_bounds__(512, 1) void gemm_qkv_fused(
    const unsigned short* __restrict__ A,    // Xb [4096][1024]
    const unsigned short* __restrict__ W,    // Wcv rows 0..3071 = q,k,v
    const float* __restrict__ bq, const float* __restrict__ bk, const float* __restrict__ bv,
    unsigned short* __restrict__ Qb)         // K at +SD, V at +2SD
{
  constexpr int BM = 256, BN = 192;
  constexpr int REGA = BM * 64;
  constexpr int BUF = REGA + BN * 64;
  __shared__ __align__(16) unsigned short LDS[2 * BUF];
  unsigned short* A0 = LDS;
  unsigned short* B0 = LDS + REGA;
  unsigned short* A1 = LDS + BUF;
  unsigned short* B1 = LDS + BUF + REGA;

  const int t = threadIdx.x;
  const int lane = t & 63, w = t >> 6;
  const int wm = w >> 2, wn = w & 3;
  const int lr = lane & 15, lg = lane >> 4;
  const int m0 = blockIdx.x * BM, n0 = blockIdx.y * BN;

  int sr[4], sc[4], sb[4];
#pragma unroll
  for (int i = 0; i < 4; ++i) {
    const int bo = (i * 512 + w * 64) * 16;
    const int o = bo + lane * 16;
    const int row = o >> 7, colb = o & 127;
    const int colp = colb ^ ((row & 3) << 4) ^ (((row >> 2) & 1) << 6);
    sr[i] = row; sc[i] = colp >> 1; sb[i] = bo >> 1;
  }

#define STAGE(e0, lA, lB)                                                           \
  do {                                                                              \
    _Pragma("unroll") for (int i = 0; i < 4; ++i)                                   \
      gload_lds16(A + (size_t)(m0 + sr[i]) * DM + (e0) + sc[i], (lA) + sb[i]);      \
    _Pragma("unroll") for (int i = 0; i < 3; ++i)                                   \
      gload_lds16(W + (size_t)(n0 + sr[i]) * DM + (e0) + sc[i], (lB) + sb[i]);      \
  } while (0)

  f32x4 acc[8][3];
#pragma unroll
  for (int m = 0; m < 8; ++m)
#pragma unroll
    for (int n = 0; n < 3; ++n) acc[m][n] = (f32x4){0.f, 0.f, 0.f, 0.f};

  const int xor6l = ((lr >> 2) & 1) << 6;
  const int xor45 = (lg << 4) ^ ((lr & 3) << 4);

#define COMPUTE(sAp, sBp)                                                           \
  do {                                                                              \
    _Pragma("unroll") for (int kk = 0; kk < 2; ++kk) {                              \
      const int coff = ((kk << 6) ^ xor6l) + xor45;                                 \
      short8 af[8], bf[3];                                                          \
      _Pragma("unroll") for (int m = 0; m < 8; ++m)                                 \
        af[m] = *(const short8*)((const char*)(sAp) + (wm * 128 + m * 16 + lr) * 128 + coff); \
      _Pragma("unroll") for (int n = 0; n < 3; ++n)                                 \
        bf[n] = *(const short8*)((const char*)(sBp) + (wn * 48 + n * 16 + lr) * 128 + coff); \
      _Pragma("unroll") for (int m = 0; m < 8; ++m)                                 \
        _Pragma("unroll") for (int n = 0; n < 3; ++n)                               \
          acc[m][n] = __builtin_amdgcn_mfma_f32_16x16x32_bf16(af[m], bf[n], acc[m][n], 0, 0, 0); \
    }                                                                               \
  } while (0)

  STAGE(0, A0, B0);
#pragma unroll 1
  for (int kt = 0; kt < 14; kt += 2) {
    STAGE((kt + 1) * 64, A1, B1);
    PIPE_WAIT7; PIPE_BAR;
    __builtin_amdgcn_s_setprio(1);
    COMPUTE(A0, B0);
    __builtin_amdgcn_s_setprio(0);
    PIPE_ENDBAR;
    STAGE((kt + 2) * 64, A0, B0);
    PIPE_WAIT7; PIPE_BAR;
    __builtin_amdgcn_s_setprio(1);
    COMPUTE(A1, B1);
    __builtin_amdgcn_s_setprio(0);
    PIPE_ENDBAR;
  }
  STAGE(15 * 64, A1, B1);
  PIPE_WAIT7; PIPE_BAR;
  __builtin_amdgcn_s_setprio(1);
  COMPUTE(A0, B0);
  __builtin_amdgcn_s_setprio(0);
  PIPE_ENDBAR;
  PIPE_WAIT0; PIPE_BAR;
  __builtin_amdgcn_s_setprio(1);
  COMPUTE(A1, B1);
  __builtin_amdgcn_s_setprio(0);

#undef STAGE
#undef COMPUTE

#pragma unroll
  for (int n = 0; n < 3; ++n) {
    const int gc = n0 + wn * 48 + n * 16 + lr;
    const int slice = gc >> 10, col = gc & 1023;
    const float* bp = (slice == 0) ? bq : (slice == 1) ? bk : bv;
    const float bv_ = bp[col];
    unsigned short* Obase = Qb + (size_t)slice * ((size_t)S_LEN * DM);
#pragma unroll
    for (int m = 0; m < 8; ++m) {
      const int gr0 = m0 + wm * 128 + m * 16 + lg * 4;
#pragma unroll
      for (int r = 0; r < 4; ++r)
        Obase[(size_t)(gr0 + r) * DM + col] = f2b(acc[m][n][r] + bv_);
    }
  }
}

// ---------------------------------------------------------------------------
// 128x128 2-phase pipelined GEMM for the output projection (round-10 form).
// ---------------------------------------------------------------------------
__global__ __launch_bounds__(256, 1) void gemm_out(
    const unsigned short* __restrict__ A,
    const unsigned short* __restrict__ Bmat,
    const float* __restrict__ bias,
    float* __restrict__ Of)
{
  constexpr int REG = 128 * 64;
  __shared__ __align__(16) unsigned short LDS[4 * REG];
  unsigned short* A0 = LDS;
  unsigned short* A1 = LDS + REG;
  unsigned short* B0 = LDS + 2 * REG;
  unsigned short* B1 = LDS + 3 * REG;

  const int t = threadIdx.x;
  const int lane = t & 63, w = t >> 6;
  const int wm = w >> 1, wn = w & 1;
  const int lr = lane & 15, lg = lane >> 4;
  const int m0 = blockIdx.x * 128, n0 = blockIdx.y * 128;

  int sr[4], sc[4], sb[4];
#pragma unroll
  for (int i = 0; i < 4; ++i) {
    const int bo = (i * 256 + w * 64) * 16;
    const int o = bo + lane * 16;
    const int row = o >> 7, colb = o & 127;
    const int colp = colb ^ ((row & 3) << 4) ^ (((row >> 2) & 1) << 6);
    sr[i] = row; sc[i] = colp >> 1; sb[i] = bo >> 1;
  }

#define STAGE(e0, lA, lB)                                                           \
  do {                                                                              \
    _Pragma("unroll") for (int i = 0; i < 4; ++i) {                                 \
      gload_lds16(A + (size_t)(m0 + sr[i]) * DM + (e0) + sc[i], (lA) + sb[i]);      \
      gload_lds16(Bmat + (size_t)(n0 + sr[i]) * DM + (e0) + sc[i], (lB) + sb[i]);   \
    }                                                                               \
  } while (0)

  f32x4 acc[4][4];
#pragma unroll
  for (int m = 0; m < 4; ++m)
#pragma unroll
    for (int n = 0; n < 4; ++n) acc[m][n] = (f32x4){0.f, 0.f, 0.f, 0.f};

  const int xor6l = ((lr >> 2) & 1) << 6;
  const int xor45 = (lg << 4) ^ ((lr & 3) << 4);

#define COMPUTE(sAp, sBp)                                                           \
  do {                                                                              \
    _Pragma("unroll") for (int kk = 0; kk < 2; ++kk) {                              \
      const int coff = ((kk << 6) ^ xor6l) + xor45;                                 \
      short8 af[4], bf[4];                                                          \
      _Pragma("unroll") for (int m = 0; m < 4; ++m)                                 \
        af[m] = *(const short8*)((const char*)(sAp) + (wm * 64 + m * 16 + lr) * 128 + coff); \
      _Pragma("unroll") for (int n = 0; n < 4; ++n)                                 \
        bf[n] = *(const short8*)((const char*)(sBp) + (wn * 64 + n * 16 + lr) * 128 + coff); \
      _Pragma("unroll") for (int m = 0; m < 4; ++m)                                 \
        _Pragma("unroll") for (int n = 0; n < 4; ++n)                               \
          acc[m][n] = __builtin_amdgcn_mfma_f32_16x16x32_bf16(af[m], bf[n], acc[m][n], 0, 0, 0); \
    }                                                                               \
  } while (0)

  STAGE(0, A0, B0);
#pragma unroll 1
  for (int kt = 0; kt < 14; kt += 2) {
    STAGE((kt + 1) * 64, A1, B1);
    PIPE_WAIT8; PIPE_BAR;
    __builtin_amdgcn_s_setprio(1);
    COMPUTE(A0, B0);
    __builtin_amdgcn_s_setprio(0);
    PIPE_ENDBAR;
    STAGE((kt + 2) * 64, A0, B0);
    PIPE_WAIT8; PIPE_BAR;
    __builtin_amdgcn_s_setprio(1);
    COMPUTE(A1, B1);
    __builtin_amdgcn_s_setprio(0);
    PIPE_ENDBAR;
  }
  STAGE(15 * 64, A1, B1);
  PIPE_WAIT8; PIPE_BAR;
  __builtin_amdgcn_s_setprio(1);
  COMPUTE(A0, B0);
  __builtin_amdgcn_s_setprio(0);
  PIPE_ENDBAR;
  PIPE_WAIT0; PIPE_BAR;
  __builtin_amdgcn_s_setprio(1);
  COMPUTE(A1, B1);
  __builtin_amdgcn_s_setprio(0);

#undef STAGE
#undef COMPUTE

#pragma unroll
  for (int n = 0; n < 4; ++n) {
    const int gc = n0 + wn * 64 + n * 16 + lr;
    const float bv = bias[gc];
#pragma unroll
    for (int m = 0; m < 4; ++m) {
      const int gr0 = m0 + wm * 64 + m * 16 + lg * 4;
#pragma unroll
      for (int r = 0; r < 4; ++r)
        Of[(size_t)(gr0 + r) * DM + gc] = acc[m][n][r] + bv;
    }
  }
}

// ---------------------------------------------------------------------------
// Sliding-window attention v5: round-10 v2 math/layout (direct global K/V
// register loads, swapped QK^T, static-max softmax, zero barriers) with
// PREFETCH DISTANCE 2: three in-flight {kf,vf} register sets and three Vt
// LDS buffers, unroll-3 rotation (static buffer names).  Latency cover per
// chunk doubles from ~1 to ~2 PROCESS phases.  +32 VGPR (grid-limited
// occupancy, no spill risk); LDS 40->60KB per block (still 2 blocks/CU).
// ---------------------------------------------------------------------------
__global__ __launch_bounds__(256) void attn(
    const unsigned short* __restrict__ Q,
    const unsigned short* __restrict__ Km,
    const unsigned short* __restrict__ Vm,
    unsigned short* __restrict__ AO)
{
  const int warp = threadIdx.x >> 6;
  const int l = threadIdx.x & 63;
  const int qw0 = (blockIdx.x * 4 + warp) * 32;
  const int hD = blockIdx.y * DH;
  const int q = l & 31;
  const int hi = l >> 5;
  const int l31 = l & 31;
  const int vkey = (l & 15) * 2;
  const int vd0 = (l >> 4) * 16;

  __shared__ __align__(16) unsigned short VtS[4][3][64 * 40];
  unsigned short* vt0 = &VtS[warp][0][0];
  unsigned short* vt1 = &VtS[warp][1][0];
  unsigned short* vt2 = &VtS[warp][2][0];

  short8 qf[4];
  {
    const unsigned short* qp = Q + (size_t)(qw0 + q) * DM + hD + hi * 8;
#pragma unroll
    for (int ks = 0; ks < 4; ++ks) qf[ks] = *(const short8*)(qp + ks * 16);
  }

  f32x16 o0{}, o1{};
  float lsum = 0.f;

  const int kb0 = (qw0 >= WIN) ? (qw0 - WIN) : 0;
  const int nch = (qw0 + 32 - kb0) >> 5;

  short8 kfA[4], vfA[4], kfB[4], vfB[4], kfC[4], vfC[4];

#define LOADKV(kb_, kf_, vf_)                                                    \
  do {                                                                           \
    const unsigned short* kp_ = Km + (size_t)((kb_) + l31) * DM + hD + hi * 8;   \
    (kf_)[0] = *(const short8*)kp_;                                              \
    (kf_)[1] = *(const short8*)(kp_ + 16);                                       \
    (kf_)[2] = *(const short8*)(kp_ + 32);                                       \
    (kf_)[3] = *(const short8*)(kp_ + 48);                                       \
    const unsigned short* vp_ = Vm + (size_t)((kb_) + vkey) * DM + hD + vd0;     \
    (vf_)[0] = *(const short8*)vp_;                                              \
    (vf_)[1] = *(const short8*)(vp_ + 8);                                        \
    (vf_)[2] = *(const short8*)(vp_ + DM);                                       \
    (vf_)[3] = *(const short8*)(vp_ + DM + 8);                                   \
  } while (0)

#define PROCESS(kb_, kf_, vf_, vt_)                                             \
  do {                                                                          \
    const int kbv = (kb_);                                                      \
    _Pragma("unroll") for (int j = 0; j < 16; ++j) {                            \
      unsigned int wv = (unsigned int)(unsigned short)(vf_)[j >> 3][j & 7]      \
          | ((unsigned int)(unsigned short)(vf_)[2 + (j >> 3)][j & 7] << 16);   \
      *(unsigned int*)((vt_) + (vd0 + j) * 40 + vkey) = wv;                     \
    }                                                                           \
    f32x16 s{};                                                                 \
    _Pragma("unroll") for (int ks = 0; ks < 4; ++ks)                            \
      s = __builtin_amdgcn_mfma_f32_32x32x16_bf16((kf_)[ks], qf[ks], s, 0, 0, 0); \
    float p[16];                                                                \
    const bool isEdge = (kbv >= qw0) || (kbv + WIN - 32 < qw0);                 \
    if (isEdge) {                                                               \
      _Pragma("unroll") for (int r = 0; r < 16; ++r) {                          \
        const int key = kbv + (r & 3) + 8 * (r >> 2) + 4 * hi;                  \
        const int qg = qw0 + q;                                                 \
        const bool valid = (key <= qg) && (qg - key < WIN);                     \
        p[r] = valid ? __expf(s[r] * 0.125f) : 0.f;                             \
        lsum += p[r];                                                           \
      }                                                                         \
    } else {                                                                    \
      _Pragma("unroll") for (int r = 0; r < 16; ++r) {                          \
        p[r] = __expf(s[r] * 0.125f);                                           \
        lsum += p[r];                                                           \
      }                                                                         \
    }                                                                           \
    unsigned int u[8];                                                          \
    _Pragma("unroll") for (int t2 = 0; t2 < 4; ++t2) {                          \
      __hip_bfloat162 h0_ = __float22bfloat162_rn(make_float2(p[4 * t2], p[4 * t2 + 1])); \
      __hip_bfloat162 h1_ = __float22bfloat162_rn(make_float2(p[4 * t2 + 2], p[4 * t2 + 3])); \
      u[2 * t2]     = *(unsigned int*)&h0_;                                     \
      u[2 * t2 + 1] = *(unsigned int*)&h1_;                                     \
    }                                                                           \
    const unsigned int sd0 = hi ? u[0] : u[2], sd1 = hi ? u[1] : u[3];          \
    const unsigned int rc0 = __shfl_xor(sd0, 32, 64), rc1 = __shfl_xor(sd1, 32, 64); \
    const unsigned int sd2 = hi ? u[4] : u[6], sd3 = hi ? u[5] : u[7];          \
    const unsigned int rc2 = __shfl_xor(sd2, 32, 64), rc3 = __shfl_xor(sd3, 32, 64); \
    i32x4 pw0, pw1;                                                             \
    pw0[0] = hi ? rc0 : u[0]; pw0[1] = hi ? rc1 : u[1];                         \
    pw0[2] = hi ? u[2] : rc0; pw0[3] = hi ? u[3] : rc1;                         \
    pw1[0] = hi ? rc2 : u[4]; pw1[1] = hi ? rc3 : u[5];                         \
    pw1[2] = hi ? u[6] : rc2; pw1[3] = hi ? u[7] : rc3;                         \
    const short8 pf0 = *(const short8*)&pw0;                                    \
    const short8 pf1 = *(const short8*)&pw1;                                    \
    const short8 a00 = *(const short8*)((vt_) + l31 * 40 + hi * 8);             \
    const short8 a01 = *(const short8*)((vt_) + l31 * 40 + 16 + hi * 8);        \
    const short8 a10 = *(const short8*)((vt_) + (32 + l31) * 40 + hi * 8);      \
    const short8 a11 = *(const short8*)((vt_) + (32 + l31) * 40 + 16 + hi * 8); \
    o0 = __builtin_amdgcn_mfma_f32_32x32x16_bf16(a00, pf0, o0, 0, 0, 0);        \
    o0 = __builtin_amdgcn_mfma_f32_32x32x16_bf16(a01, pf1, o0, 0, 0, 0);        \
    o1 = __builtin_amdgcn_mfma_f32_32x32x16_bf16(a10, pf0, o1, 0, 0, 0);        \
    o1 = __builtin_amdgcn_mfma_f32_32x32x16_bf16(a11, pf1, o1, 0, 0, 0);        \
  } while (0)

  // prologue: prefetch chunks 0 and 1
  LOADKV(kb0, kfA, vfA);
  if (nch > 1) LOADKV(kb0 + 32, kfB, vfB);
  int c = 0;
#pragma unroll 1
  for (; c + 3 <= nch; c += 3) {
    const int kb = kb0 + c * 32;
    LOADKV(kb + 64, kfC, vfC);                       // prefetch c+2
    PROCESS(kb, kfA, vfA, vt0);
    if (c + 3 < nch) LOADKV(kb + 96, kfA, vfA);      // prefetch c+3
    PROCESS(kb + 32, kfB, vfB, vt1);
    if (c + 4 < nch) LOADKV(kb + 128, kfB, vfB);     // prefetch c+4
    PROCESS(kb + 64, kfC, vfC, vt2);
  }
  if (c < nch)     PROCESS(kb0 + c * 32, kfA, vfA, vt0);
  if (c + 1 < nch) PROCESS(kb0 + (c + 1) * 32, kfB, vfB, vt1);

#undef LOADKV
#undef PROCESS

  lsum += __shfl_xor(lsum, 32, 64);
  const float inv = 1.f / lsum;
  unsigned short* aop = AO + (size_t)(qw0 + q) * DM + hD;
#pragma unroll
  for (int t2 = 0; t2 < 4; ++t2) {
    __hip_bfloat162 s0 = __float22bfloat162_rn(make_float2(o0[4*t2] * inv, o0[4*t2+1] * inv));
    __hip_bfloat162 s1 = __float22bfloat162_rn(make_float2(o0[4*t2+2] * inv, o0[4*t2+3] * inv));
    uint2 st; st.x = *(unsigned int*)&s0; st.y = *(unsigned int*)&s1;
    *(uint2*)(aop + 8 * t2 + 4 * hi) = st;
    __hip_bfloat162 s2 = __float22bfloat162_rn(make_float2(o1[4*t2] * inv, o1[4*t2+1] * inv));
    __hip_bfloat162 s3 = __float22bfloat162_rn(make_float2(o1[4*t2+2] * inv, o1[4*t2+3] * inv));
    uint2 st2; st2.x = *(unsigned int*)&s2; st2.y = *(unsigned int*)&s3;
    *(uint2*)(aop + 32 + 8 * t2 + 4 * hi) = st2;
  }
}

// ---------------------------------------------------------------------------
extern "C" void kernel_launch(void* const* d_in, const int* in_sizes, int n_in,
                              void* d_out, int out_size, void* d_ws, size_t ws_size,
                              hipStream_t stream) {
  const float* x  = (const float*)d_in[0];
  const float* qw = (const float*)d_in[1];
  const float* qb = (const float*)d_in[2];
  const float* kw = (const float*)d_in[3];
  const float* kb = (const float*)d_in[4];
  const float* vw = (const float*)d_in[5];
  const float* vb = (const float*)d_in[6];
  const float* ow = (const float*)d_in[7];
  const float* ob = (const float*)d_in[8];

  const size_t SD = (size_t)S_LEN * DM;
  unsigned short* Qb  = (unsigned short*)d_ws;
  unsigned short* Kb  = Qb + SD;
  unsigned short* Vb  = Kb + SD;
  unsigned short* AOb = Vb + SD;
  unsigned short* Xb  = AOb + SD;
  unsigned short* Wcv = Xb + SD;

  cvt_all<<<dim3(2048, 5), 256, 0, stream>>>(x, qw, kw, vw, ow, Xb, Wcv);
  gemm_qkv_fused<<<dim3(16, 16), 512, 0, stream>>>(Xb, Wcv, qb, kb, vb, Qb);
  attn<<<dim3(S_LEN / 128, NH), 256, 0, stream>>>(Qb, Kb, Vb, AOb);
  gemm_out<<<dim3(32, 8), 256, 0, stream>>>(AOb, Wcv + (size_t)3 * DM * DM, ob, (float*)d_out);
}

// Round 18
// 81.475 us; speedup vs baseline: 1.0859x; 1.0047x over previous
//
#include <hip/hip_runtime.h>
#include <hip/hip_bf16.h>

typedef __attribute__((ext_vector_type(4))) float f32x4;
typedef __attribute__((ext_vector_type(16))) float f32x16;
typedef __attribute__((ext_vector_type(8))) short short8;
typedef __attribute__((ext_vector_type(4))) int i32x4;

#define S_LEN 4096
#define DM    1024
#define NH    16
#define DH    64
#define WIN   256

__device__ inline unsigned short f2b(float f) {
  unsigned int x = __float_as_uint(f);
  unsigned int r = (x + 0x7fffu + ((x >> 16) & 1u)) >> 16;
  return (unsigned short)r;
}

__device__ inline void gload_lds16(const void* g, void* l) {
  __builtin_amdgcn_global_load_lds(
      (const __attribute__((address_space(1))) void*)g,
      (__attribute__((address_space(3))) void*)l, 16, 0, 0);
}

// ---------------------------------------------------------------------------
// Convert X and the 4 weight matrices f32 -> bf16.
// ---------------------------------------------------------------------------
__global__ __launch_bounds__(256) void cvt_all(
    const float* __restrict__ x,
    const float* __restrict__ qw, const float* __restrict__ kw,
    const float* __restrict__ vw, const float* __restrict__ ow,
    unsigned short* __restrict__ Xb, unsigned short* __restrict__ Wb)
{
  const int y = blockIdx.y;
  const float* src;
  unsigned short* dst;
  int n8;
  if (y == 0) { src = x; dst = Xb; n8 = (S_LEN * DM) / 8; }
  else {
    src = (y == 1) ? qw : (y == 2) ? kw : (y == 3) ? vw : ow;
    dst = Wb + (size_t)(y - 1) * DM * DM;
    n8 = (DM * DM) / 8;
  }
  const int i = blockIdx.x * 256 + threadIdx.x;
  if (i >= n8) return;
  const float4* s4 = (const float4*)src + (size_t)i * 2;
  float4 a = s4[0], b = s4[1];
  short8 v;
  v[0] = f2b(a.x); v[1] = f2b(a.y); v[2] = f2b(a.z); v[3] = f2b(a.w);
  v[4] = f2b(b.x); v[5] = f2b(b.y); v[6] = f2b(b.z); v[7] = f2b(b.w);
  *(short8*)(dst + (size_t)i * 8) = v;
}

#define PIPE_WAIT8  asm volatile("s_waitcnt vmcnt(8)" ::: "memory")
#define PIPE_WAIT7  asm volatile("s_waitcnt vmcnt(7)" ::: "memory")
#define PIPE_WAIT0  asm volatile("s_waitcnt vmcnt(0)" ::: "memory")
#define PIPE_BAR    do { __builtin_amdgcn_s_barrier(); __builtin_amdgcn_sched_barrier(0); } while (0)
#define PIPE_ENDBAR do { __builtin_amdgcn_sched_barrier(0); __builtin_amdgcn_s_barrier(); \
                         __builtin_amdgcn_sched_barrier(0); } while (0)

// ---------------------------------------------------------------------------
// Fused QKV GEMM (4096x3072), BM=256 BN=192, grid 16x16 = 256 blocks = 1/CU,
// 2-phase counted-vmcnt pipeline (round-10 measured-best form).
// ---------------------------------------------------------------------------
__global__ __launch_bounds__(512, 1) void gemm_qkv_fused(
    const unsigned short* __restrict__ A,    // Xb [4096][1024]
    const unsigned short* __restrict__ W,    // Wcv rows 0..3071 = q,k,v
    const float* __restrict__ bq, const float* __restrict__ bk, const float* __restrict__ bv,
    unsigned short* __restrict__ Qb)         // K at +SD, V at +2SD
{
  constexpr int BM = 256, BN = 192;
  constexpr int REGA = BM * 64;
  constexpr int BUF = REGA + BN * 64;
  __shared__ __align__(16) unsigned short LDS[2 * BUF];
  unsigned short* A0 = LDS;
  unsigned short* B0 = LDS + REGA;
  unsigned short* A1 = LDS + BUF;
  unsigned short* B1 = LDS + BUF + REGA;

  const int t = threadIdx.x;
  const int lane = t & 63, w = t >> 6;
  const int wm = w >> 2, wn = w & 3;
  const int lr = lane & 15, lg = lane >> 4;
  const int m0 = blockIdx.x * BM, n0 = blockIdx.y * BN;

  int sr[4], sc[4], sb[4];
#pragma unroll
  for (int i = 0; i < 4; ++i) {
    const int bo = (i * 512 + w * 64) * 16;
    const int o = bo + lane * 16;
    const int row = o >> 7, colb = o & 127;
    const int colp = colb ^ ((row & 3) << 4) ^ (((row >> 2) & 1) << 6);
    sr[i] = row; sc[i] = colp >> 1; sb[i] = bo >> 1;
  }

#define STAGE(e0, lA, lB)                                                           \
  do {                                                                              \
    _Pragma("unroll") for (int i = 0; i < 4; ++i)                                   \
      gload_lds16(A + (size_t)(m0 + sr[i]) * DM + (e0) + sc[i], (lA) + sb[i]);      \
    _Pragma("unroll") for (int i = 0; i < 3; ++i)                                   \
      gload_lds16(W + (size_t)(n0 + sr[i]) * DM + (e0) + sc[i], (lB) + sb[i]);      \
  } while (0)

  f32x4 acc[8][3];
#pragma unroll
  for (int m = 0; m < 8; ++m)
#pragma unroll
    for (int n = 0; n < 3; ++n) acc[m][n] = (f32x4){0.f, 0.f, 0.f, 0.f};

  const int xor6l = ((lr >> 2) & 1) << 6;
  const int xor45 = (lg << 4) ^ ((lr & 3) << 4);

#define COMPUTE(sAp, sBp)                                                           \
  do {                                                                              \
    _Pragma("unroll") for (int kk = 0; kk < 2; ++kk) {                              \
      const int coff = ((kk << 6) ^ xor6l) + xor45;                                 \
      short8 af[8], bf[3];                                                          \
      _Pragma("unroll") for (int m = 0; m < 8; ++m)                                 \
        af[m] = *(const short8*)((const char*)(sAp) + (wm * 128 + m * 16 + lr) * 128 + coff); \
      _Pragma("unroll") for (int n = 0; n < 3; ++n)                                 \
        bf[n] = *(const short8*)((const char*)(sBp) + (wn * 48 + n * 16 + lr) * 128 + coff); \
      _Pragma("unroll") for (int m = 0; m < 8; ++m)                                 \
        _Pragma("unroll") for (int n = 0; n < 3; ++n)                               \
          acc[m][n] = __builtin_amdgcn_mfma_f32_16x16x32_bf16(af[m], bf[n], acc[m][n], 0, 0, 0); \
    }                                                                               \
  } while (0)

  STAGE(0, A0, B0);
#pragma unroll 1
  for (int kt = 0; kt < 14; kt += 2) {
    STAGE((kt + 1) * 64, A1, B1);
    PIPE_WAIT7; PIPE_BAR;
    __builtin_amdgcn_s_setprio(1);
    COMPUTE(A0, B0);
    __builtin_amdgcn_s_setprio(0);
    PIPE_ENDBAR;
    STAGE((kt + 2) * 64, A0, B0);
    PIPE_WAIT7; PIPE_BAR;
    __builtin_amdgcn_s_setprio(1);
    COMPUTE(A1, B1);
    __builtin_amdgcn_s_setprio(0);
    PIPE_ENDBAR;
  }
  STAGE(15 * 64, A1, B1);
  PIPE_WAIT7; PIPE_BAR;
  __builtin_amdgcn_s_setprio(1);
  COMPUTE(A0, B0);
  __builtin_amdgcn_s_setprio(0);
  PIPE_ENDBAR;
  PIPE_WAIT0; PIPE_BAR;
  __builtin_amdgcn_s_setprio(1);
  COMPUTE(A1, B1);
  __builtin_amdgcn_s_setprio(0);

#undef STAGE
#undef COMPUTE

#pragma unroll
  for (int n = 0; n < 3; ++n) {
    const int gc = n0 + wn * 48 + n * 16 + lr;
    const int slice = gc >> 10, col = gc & 1023;
    const float* bp = (slice == 0) ? bq : (slice == 1) ? bk : bv;
    const float bv_ = bp[col];
    unsigned short* Obase = Qb + (size_t)slice * ((size_t)S_LEN * DM);
#pragma unroll
    for (int m = 0; m < 8; ++m) {
      const int gr0 = m0 + wm * 128 + m * 16 + lg * 4;
#pragma unroll
      for (int r = 0; r < 4; ++r)
        Obase[(size_t)(gr0 + r) * DM + col] = f2b(acc[m][n][r] + bv_);
    }
  }
}

// ---------------------------------------------------------------------------
// 128x128 2-phase pipelined GEMM for the output projection (round-10 form).
// ---------------------------------------------------------------------------
__global__ __launch_bounds__(256, 1) void gemm_out(
    const unsigned short* __restrict__ A,
    const unsigned short* __restrict__ Bmat,
    const float* __restrict__ bias,
    float* __restrict__ Of)
{
  constexpr int REG = 128 * 64;
  __shared__ __align__(16) unsigned short LDS[4 * REG];
  unsigned short* A0 = LDS;
  unsigned short* A1 = LDS + REG;
  unsigned short* B0 = LDS + 2 * REG;
  unsigned short* B1 = LDS + 3 * REG;

  const int t = threadIdx.x;
  const int lane = t & 63, w = t >> 6;
  const int wm = w >> 1, wn = w & 1;
  const int lr = lane & 15, lg = lane >> 4;
  const int m0 = blockIdx.x * 128, n0 = blockIdx.y * 128;

  int sr[4], sc[4], sb[4];
#pragma unroll
  for (int i = 0; i < 4; ++i) {
    const int bo = (i * 256 + w * 64) * 16;
    const int o = bo + lane * 16;
    const int row = o >> 7, colb = o & 127;
    const int colp = colb ^ ((row & 3) << 4) ^ (((row >> 2) & 1) << 6);
    sr[i] = row; sc[i] = colp >> 1; sb[i] = bo >> 1;
  }

#define STAGE(e0, lA, lB)                                                           \
  do {                                                                              \
    _Pragma("unroll") for (int i = 0; i < 4; ++i) {                                 \
      gload_lds16(A + (size_t)(m0 + sr[i]) * DM + (e0) + sc[i], (lA) + sb[i]);      \
      gload_lds16(Bmat + (size_t)(n0 + sr[i]) * DM + (e0) + sc[i], (lB) + sb[i]);   \
    }                                                                               \
  } while (0)

  f32x4 acc[4][4];
#pragma unroll
  for (int m = 0; m < 4; ++m)
#pragma unroll
    for (int n = 0; n < 4; ++n) acc[m][n] = (f32x4){0.f, 0.f, 0.f, 0.f};

  const int xor6l = ((lr >> 2) & 1) << 6;
  const int xor45 = (lg << 4) ^ ((lr & 3) << 4);

#define COMPUTE(sAp, sBp)                                                           \
  do {                                                                              \
    _Pragma("unroll") for (int kk = 0; kk < 2; ++kk) {                              \
      const int coff = ((kk << 6) ^ xor6l) + xor45;                                 \
      short8 af[4], bf[4];                                                          \
      _Pragma("unroll") for (int m = 0; m < 4; ++m)                                 \
        af[m] = *(const short8*)((const char*)(sAp) + (wm * 64 + m * 16 + lr) * 128 + coff); \
      _Pragma("unroll") for (int n = 0; n < 4; ++n)                                 \
        bf[n] = *(const short8*)((const char*)(sBp) + (wn * 64 + n * 16 + lr) * 128 + coff); \
      _Pragma("unroll") for (int m = 0; m < 4; ++m)                                 \
        _Pragma("unroll") for (int n = 0; n < 4; ++n)                               \
          acc[m][n] = __builtin_amdgcn_mfma_f32_16x16x32_bf16(af[m], bf[n], acc[m][n], 0, 0, 0); \
    }                                                                               \
  } while (0)

  STAGE(0, A0, B0);
#pragma unroll 1
  for (int kt = 0; kt < 14; kt += 2) {
    STAGE((kt + 1) * 64, A1, B1);
    PIPE_WAIT8; PIPE_BAR;
    __builtin_amdgcn_s_setprio(1);
    COMPUTE(A0, B0);
    __builtin_amdgcn_s_setprio(0);
    PIPE_ENDBAR;
    STAGE((kt + 2) * 64, A0, B0);
    PIPE_WAIT8; PIPE_BAR;
    __builtin_amdgcn_s_setprio(1);
    COMPUTE(A1, B1);
    __builtin_amdgcn_s_setprio(0);
    PIPE_ENDBAR;
  }
  STAGE(15 * 64, A1, B1);
  PIPE_WAIT8; PIPE_BAR;
  __builtin_amdgcn_s_setprio(1);
  COMPUTE(A0, B0);
  __builtin_amdgcn_s_setprio(0);
  PIPE_ENDBAR;
  PIPE_WAIT0; PIPE_BAR;
  __builtin_amdgcn_s_setprio(1);
  COMPUTE(A1, B1);
  __builtin_amdgcn_s_setprio(0);

#undef STAGE
#undef COMPUTE

#pragma unroll
  for (int n = 0; n < 4; ++n) {
    const int gc = n0 + wn * 64 + n * 16 + lr;
    const float bv = bias[gc];
#pragma unroll
    for (int m = 0; m < 4; ++m) {
      const int gr0 = m0 + wm * 64 + m * 16 + lg * 4;
#pragma unroll
      for (int r = 0; r < 4; ++r)
        Of[(size_t)(gr0 + r) * DM + gc] = acc[m][n][r] + bv;
    }
  }
}

// ---------------------------------------------------------------------------
// Sliding-window attention v2 (measured-best): 1 warp per 32 q-rows,
// 32x32x16 MFMA, swapped QK^T (lane owns one query column), static-max
// softmax (scores bounded -> exp(s)/sum exact, no running max), zero
// barriers (per-warp private double-buffered V^T LDS), K/V prefetch
// distance 1, cvt_pk packing.
// ---------------------------------------------------------------------------
__global__ __launch_bounds__(256) void attn(
    const unsigned short* __restrict__ Q,
    const unsigned short* __restrict__ Km,
    const unsigned short* __restrict__ Vm,
    unsigned short* __restrict__ AO)
{
  const int warp = threadIdx.x >> 6;
  const int l = threadIdx.x & 63;
  const int qw0 = (blockIdx.x * 4 + warp) * 32;
  const int hD = blockIdx.y * DH;
  const int q = l & 31;
  const int hi = l >> 5;
  const int l31 = l & 31;
  const int vkey = (l & 15) * 2;
  const int vd0 = (l >> 4) * 16;

  __shared__ __align__(16) unsigned short VtS[4][2][64 * 40];
  unsigned short* vt0 = &VtS[warp][0][0];
  unsigned short* vt1 = &VtS[warp][1][0];

  short8 qf[4];
  {
    const unsigned short* qp = Q + (size_t)(qw0 + q) * DM + hD + hi * 8;
#pragma unroll
    for (int ks = 0; ks < 4; ++ks) qf[ks] = *(const short8*)(qp + ks * 16);
  }

  f32x16 o0{}, o1{};
  float lsum = 0.f;

  const int kb0 = (qw0 >= WIN) ? (qw0 - WIN) : 0;
  const int nch = (qw0 + 32 - kb0) >> 5;

  short8 kfA[4], vfA[4], kfB[4], vfB[4];

#define LOADKV(kb_, kf_, vf_)                                                    \
  do {                                                                           \
    const unsigned short* kp_ = Km + (size_t)((kb_) + l31) * DM + hD + hi * 8;   \
    (kf_)[0] = *(const short8*)kp_;                                              \
    (kf_)[1] = *(const short8*)(kp_ + 16);                                       \
    (kf_)[2] = *(const short8*)(kp_ + 32);                                       \
    (kf_)[3] = *(const short8*)(kp_ + 48);                                       \
    const unsigned short* vp_ = Vm + (size_t)((kb_) + vkey) * DM + hD + vd0;     \
    (vf_)[0] = *(const short8*)vp_;                                              \
    (vf_)[1] = *(const short8*)(vp_ + 8);                                        \
    (vf_)[2] = *(const short8*)(vp_ + DM);                                       \
    (vf_)[3] = *(const short8*)(vp_ + DM + 8);                                   \
  } while (0)

#define PROCESS(kb_, kf_, vf_, vt_)                                             \
  do {                                                                          \
    const int kbv = (kb_);                                                      \
    _Pragma("unroll") for (int j = 0; j < 16; ++j) {                            \
      unsigned int wv = (unsigned int)(unsigned short)(vf_)[j >> 3][j & 7]      \
          | ((unsigned int)(unsigned short)(vf_)[2 + (j >> 3)][j & 7] << 16);   \
      *(unsigned int*)((vt_) + (vd0 + j) * 40 + vkey) = wv;                     \
    }                                                                           \
    f32x16 s{};                                                                 \
    _Pragma("unroll") for (int ks = 0; ks < 4; ++ks)                            \
      s = __builtin_amdgcn_mfma_f32_32x32x16_bf16((kf_)[ks], qf[ks], s, 0, 0, 0); \
    float p[16];                                                                \
    const bool isEdge = (kbv >= qw0) || (kbv + WIN - 32 < qw0);                 \
    if (isEdge) {                                                               \
      _Pragma("unroll") for (int r = 0; r < 16; ++r) {                          \
        const int key = kbv + (r & 3) + 8 * (r >> 2) + 4 * hi;                  \
        const int qg = qw0 + q;                                                 \
        const bool valid = (key <= qg) && (qg - key < WIN);                     \
        p[r] = valid ? __expf(s[r] * 0.125f) : 0.f;                             \
        lsum += p[r];                                                           \
      }                                                                         \
    } else {                                                                    \
      _Pragma("unroll") for (int r = 0; r < 16; ++r) {                          \
        p[r] = __expf(s[r] * 0.125f);                                           \
        lsum += p[r];                                                           \
      }                                                                         \
    }                                                                           \
    unsigned int u[8];                                                          \
    _Pragma("unroll") for (int t2 = 0; t2 < 4; ++t2) {                          \
      __hip_bfloat162 h0_ = __float22bfloat162_rn(make_float2(p[4 * t2], p[4 * t2 + 1])); \
      __hip_bfloat162 h1_ = __float22bfloat162_rn(make_float2(p[4 * t2 + 2], p[4 * t2 + 3])); \
      u[2 * t2]     = *(unsigned int*)&h0_;                                     \
      u[2 * t2 + 1] = *(unsigned int*)&h1_;                                     \
    }                                                                           \
    const unsigned int sd0 = hi ? u[0] : u[2], sd1 = hi ? u[1] : u[3];          \
    const unsigned int rc0 = __shfl_xor(sd0, 32, 64), rc1 = __shfl_xor(sd1, 32, 64); \
    const unsigned int sd2 = hi ? u[4] : u[6], sd3 = hi ? u[5] : u[7];          \
    const unsigned int rc2 = __shfl_xor(sd2, 32, 64), rc3 = __shfl_xor(sd3, 32, 64); \
    i32x4 pw0, pw1;                                                             \
    pw0[0] = hi ? rc0 : u[0]; pw0[1] = hi ? rc1 : u[1];                         \
    pw0[2] = hi ? u[2] : rc0; pw0[3] = hi ? u[3] : rc1;                         \
    pw1[0] = hi ? rc2 : u[4]; pw1[1] = hi ? rc3 : u[5];                         \
    pw1[2] = hi ? u[6] : rc2; pw1[3] = hi ? u[7] : rc3;                         \
    const short8 pf0 = *(const short8*)&pw0;                                    \
    const short8 pf1 = *(const short8*)&pw1;                                    \
    const short8 a00 = *(const short8*)((vt_) + l31 * 40 + hi * 8);             \
    const short8 a01 = *(const short8*)((vt_) + l31 * 40 + 16 + hi * 8);        \
    const short8 a10 = *(const short8*)((vt_) + (32 + l31) * 40 + hi * 8);      \
    const short8 a11 = *(const short8*)((vt_) + (32 + l31) * 40 + 16 + hi * 8); \
    o0 = __builtin_amdgcn_mfma_f32_32x32x16_bf16(a00, pf0, o0, 0, 0, 0);        \
    o0 = __builtin_amdgcn_mfma_f32_32x32x16_bf16(a01, pf1, o0, 0, 0, 0);        \
    o1 = __builtin_amdgcn_mfma_f32_32x32x16_bf16(a10, pf0, o1, 0, 0, 0);        \
    o1 = __builtin_amdgcn_mfma_f32_32x32x16_bf16(a11, pf1, o1, 0, 0, 0);        \
  } while (0)

  LOADKV(kb0, kfA, vfA);
  int c = 0;
#pragma unroll 1
  for (; c + 2 <= nch; c += 2) {
    const int kb = kb0 + c * 32;
    LOADKV(kb + 32, kfB, vfB);
    PROCESS(kb, kfA, vfA, vt0);
    if (c + 2 < nch) LOADKV(kb + 64, kfA, vfA);
    PROCESS(kb + 32, kfB, vfB, vt1);
  }
  if (c < nch) PROCESS(kb0 + c * 32, kfA, vfA, vt0);

#undef LOADKV
#undef PROCESS

  lsum += __shfl_xor(lsum, 32, 64);
  const float inv = 1.f / lsum;
  unsigned short* aop = AO + (size_t)(qw0 + q) * DM + hD;
#pragma unroll
  for (int t2 = 0; t2 < 4; ++t2) {
    __hip_bfloat162 s0 = __float22bfloat162_rn(make_float2(o0[4*t2] * inv, o0[4*t2+1] * inv));
    __hip_bfloat162 s1 = __float22bfloat162_rn(make_float2(o0[4*t2+2] * inv, o0[4*t2+3] * inv));
    uint2 st; st.x = *(unsigned int*)&s0; st.y = *(unsigned int*)&s1;
    *(uint2*)(aop + 8 * t2 + 4 * hi) = st;
    __hip_bfloat162 s2 = __float22bfloat162_rn(make_float2(o1[4*t2] * inv, o1[4*t2+1] * inv));
    __hip_bfloat162 s3 = __float22bfloat162_rn(make_float2(o1[4*t2+2] * inv, o1[4*t2+3] * inv));
    uint2 st2; st2.x = *(unsigned int*)&s2; st2.y = *(unsigned int*)&s3;
    *(uint2*)(aop + 32 + 8 * t2 + 4 * hi) = st2;
  }
}

// ---------------------------------------------------------------------------
extern "C" void kernel_launch(void* const* d_in, const int* in_sizes, int n_in,
                              void* d_out, int out_size, void* d_ws, size_t ws_size,
                              hipStream_t stream) {
  const float* x  = (const float*)d_in[0];
  const float* qw = (const float*)d_in[1];
  const float* qb = (const float*)d_in[2];
  const float* kw = (const float*)d_in[3];
  const float* kb = (const float*)d_in[4];
  const float* vw = (const float*)d_in[5];
  const float* vb = (const float*)d_in[6];
  const float* ow = (const float*)d_in[7];
  const float* ob = (const float*)d_in[8];

  const size_t SD = (size_t)S_LEN * DM;
  unsigned short* Qb  = (unsigned short*)d_ws;
  unsigned short* Kb  = Qb + SD;
  unsigned short* Vb  = Kb + SD;
  unsigned short* AOb = Vb + SD;
  unsigned short* Xb  = AOb + SD;
  unsigned short* Wcv = Xb + SD;

  cvt_all<<<dim3(2048, 5), 256, 0, stream>>>(x, qw, kw, vw, ow, Xb, Wcv);
  gemm_qkv_fused<<<dim3(16, 16), 512, 0, stream>>>(Xb, Wcv, qb, kb, vb, Qb);
  attn<<<dim3(S_LEN / 128, NH), 256, 0, stream>>>(Qb, Kb, Vb, AOb);
  gemm_out<<<dim3(32, 8), 256, 0, stream>>>(AOb, Wcv + (size_t)3 * DM * DM, ob, (float*)d_out);
}

// Round 19
// 79.552 us; speedup vs baseline: 1.1122x; 1.0242x over previous
//
#include <hip/hip_runtime.h>
#include <hip/hip_bf16.h>

typedef __attribute__((ext_vector_type(4))) float f32x4;
typedef __attribute__((ext_vector_type(16))) float f32x16;
typedef __attribute__((ext_vector_type(8))) short short8;
typedef __attribute__((ext_vector_type(4))) int i32x4;

#define S_LEN 4096
#define DM    1024
#define NH    16
#define DH    64
#define WIN   256

__device__ inline unsigned short f2b(float f) {
  unsigned int x = __float_as_uint(f);
  unsigned int r = (x + 0x7fffu + ((x >> 16) & 1u)) >> 16;
  return (unsigned short)r;
}

__device__ inline void gload_lds16(const void* g, void* l) {
  __builtin_amdgcn_global_load_lds(
      (const __attribute__((address_space(1))) void*)g,
      (__attribute__((address_space(3))) void*)l, 16, 0, 0);
}

// ---------------------------------------------------------------------------
// Convert X and the 4 weight matrices f32 -> bf16.
// ---------------------------------------------------------------------------
__global__ __launch_bounds__(256) void cvt_all(
    const float* __restrict__ x,
    const float* __restrict__ qw, const float* __restrict__ kw,
    const float* __restrict__ vw, const float* __restrict__ ow,
    unsigned short* __restrict__ Xb, unsigned short* __restrict__ Wb)
{
  const int y = blockIdx.y;
  const float* src;
  unsigned short* dst;
  int n8;
  if (y == 0) { src = x; dst = Xb; n8 = (S_LEN * DM) / 8; }
  else {
    src = (y == 1) ? qw : (y == 2) ? kw : (y == 3) ? vw : ow;
    dst = Wb + (size_t)(y - 1) * DM * DM;
    n8 = (DM * DM) / 8;
  }
  const int i = blockIdx.x * 256 + threadIdx.x;
  if (i >= n8) return;
  const float4* s4 = (const float4*)src + (size_t)i * 2;
  float4 a = s4[0], b = s4[1];
  short8 v;
  v[0] = f2b(a.x); v[1] = f2b(a.y); v[2] = f2b(a.z); v[3] = f2b(a.w);
  v[4] = f2b(b.x); v[5] = f2b(b.y); v[6] = f2b(b.z); v[7] = f2b(b.w);
  *(short8*)(dst + (size_t)i * 8) = v;
}

#define PIPE_WAIT8  asm volatile("s_waitcnt vmcnt(8)" ::: "memory")
#define PIPE_WAIT7  asm volatile("s_waitcnt vmcnt(7)" ::: "memory")
#define PIPE_WAIT0  asm volatile("s_waitcnt vmcnt(0)" ::: "memory")
#define PIPE_BAR    do { __builtin_amdgcn_s_barrier(); __builtin_amdgcn_sched_barrier(0); } while (0)
#define PIPE_ENDBAR do { __builtin_amdgcn_sched_barrier(0); __builtin_amdgcn_s_barrier(); \
                         __builtin_amdgcn_sched_barrier(0); } while (0)

// ---------------------------------------------------------------------------
// Fused QKV GEMM (4096x3072), BM=256 BN=192, grid 16x16 = 256 blocks = 1/CU,
// 2-phase counted-vmcnt pipeline (round-10 measured-best form).
// ---------------------------------------------------------------------------
__global__ __launch_bounds__(512, 1) void gemm_qkv_fused(
    const unsigned short* __restrict__ A,    // Xb [4096][1024]
    const unsigned short* __restrict__ W,    // Wcv rows 0..3071 = q,k,v
    const float* __restrict__ bq, const float* __restrict__ bk, const float* __restrict__ bv,
    unsigned short* __restrict__ Qb)         // K at +SD, V at +2SD
{
  constexpr int BM = 256, BN = 192;
  constexpr int REGA = BM * 64;
  constexpr int BUF = REGA + BN * 64;
  __shared__ __align__(16) unsigned short LDS[2 * BUF];
  unsigned short* A0 = LDS;
  unsigned short* B0 = LDS + REGA;
  unsigned short* A1 = LDS + BUF;
  unsigned short* B1 = LDS + BUF + REGA;

  const int t = threadIdx.x;
  const int lane = t & 63, w = t >> 6;
  const int wm = w >> 2, wn = w & 3;
  const int lr = lane & 15, lg = lane >> 4;
  const int m0 = blockIdx.x * BM, n0 = blockIdx.y * BN;

  int sr[4], sc[4], sb[4];
#pragma unroll
  for (int i = 0; i < 4; ++i) {
    const int bo = (i * 512 + w * 64) * 16;
    const int o = bo + lane * 16;
    const int row = o >> 7, colb = o & 127;
    const int colp = colb ^ ((row & 3) << 4) ^ (((row >> 2) & 1) << 6);
    sr[i] = row; sc[i] = colp >> 1; sb[i] = bo >> 1;
  }

#define STAGE(e0, lA, lB)                                                           \
  do {                                                                              \
    _Pragma("unroll") for (int i = 0; i < 4; ++i)                                   \
      gload_lds16(A + (size_t)(m0 + sr[i]) * DM + (e0) + sc[i], (lA) + sb[i]);      \
    _Pragma("unroll") for (int i = 0; i < 3; ++i)                                   \
      gload_lds16(W + (size_t)(n0 + sr[i]) * DM + (e0) + sc[i], (lB) + sb[i]);      \
  } while (0)

  f32x4 acc[8][3];
#pragma unroll
  for (int m = 0; m < 8; ++m)
#pragma unroll
    for (int n = 0; n < 3; ++n) acc[m][n] = (f32x4){0.f, 0.f, 0.f, 0.f};

  const int xor6l = ((lr >> 2) & 1) << 6;
  const int xor45 = (lg << 4) ^ ((lr & 3) << 4);

#define COMPUTE(sAp, sBp)                                                           \
  do {                                                                              \
    _Pragma("unroll") for (int kk = 0; kk < 2; ++kk) {                              \
      const int coff = ((kk << 6) ^ xor6l) + xor45;                                 \
      short8 af[8], bf[3];                                                          \
      _Pragma("unroll") for (int m = 0; m < 8; ++m)                                 \
        af[m] = *(const short8*)((const char*)(sAp) + (wm * 128 + m * 16 + lr) * 128 + coff); \
      _Pragma("unroll") for (int n = 0; n < 3; ++n)                                 \
        bf[n] = *(const short8*)((const char*)(sBp) + (wn * 48 + n * 16 + lr) * 128 + coff); \
      _Pragma("unroll") for (int m = 0; m < 8; ++m)                                 \
        _Pragma("unroll") for (int n = 0; n < 3; ++n)                               \
          acc[m][n] = __builtin_amdgcn_mfma_f32_16x16x32_bf16(af[m], bf[n], acc[m][n], 0, 0, 0); \
    }                                                                               \
  } while (0)

  STAGE(0, A0, B0);
#pragma unroll 1
  for (int kt = 0; kt < 14; kt += 2) {
    STAGE((kt + 1) * 64, A1, B1);
    PIPE_WAIT7; PIPE_BAR;
    __builtin_amdgcn_s_setprio(1);
    COMPUTE(A0, B0);
    __builtin_amdgcn_s_setprio(0);
    PIPE_ENDBAR;
    STAGE((kt + 2) * 64, A0, B0);
    PIPE_WAIT7; PIPE_BAR;
    __builtin_amdgcn_s_setprio(1);
    COMPUTE(A1, B1);
    __builtin_amdgcn_s_setprio(0);
    PIPE_ENDBAR;
  }
  STAGE(15 * 64, A1, B1);
  PIPE_WAIT7; PIPE_BAR;
  __builtin_amdgcn_s_setprio(1);
  COMPUTE(A0, B0);
  __builtin_amdgcn_s_setprio(0);
  PIPE_ENDBAR;
  PIPE_WAIT0; PIPE_BAR;
  __builtin_amdgcn_s_setprio(1);
  COMPUTE(A1, B1);
  __builtin_amdgcn_s_setprio(0);

#undef STAGE
#undef COMPUTE

#pragma unroll
  for (int n = 0; n < 3; ++n) {
    const int gc = n0 + wn * 48 + n * 16 + lr;
    const int slice = gc >> 10, col = gc & 1023;
    const float* bp = (slice == 0) ? bq : (slice == 1) ? bk : bv;
    const float bv_ = bp[col];
    unsigned short* Obase = Qb + (size_t)slice * ((size_t)S_LEN * DM);
#pragma unroll
    for (int m = 0; m < 8; ++m) {
      const int gr0 = m0 + wm * 128 + m * 16 + lg * 4;
#pragma unroll
      for (int r = 0; r < 4; ++r)
        Obase[(size_t)(gr0 + r) * DM + col] = f2b(acc[m][n][r] + bv_);
    }
  }
}

// ---------------------------------------------------------------------------
// 128x128 2-phase pipelined GEMM for the output projection (round-10 form).
// ---------------------------------------------------------------------------
__global__ __launch_bounds__(256, 1) void gemm_out(
    const unsigned short* __restrict__ A,
    const unsigned short* __restrict__ Bmat,
    const float* __restrict__ bias,
    float* __restrict__ Of)
{
  constexpr int REG = 128 * 64;
  __shared__ __align__(16) unsigned short LDS[4 * REG];
  unsigned short* A0 = LDS;
  unsigned short* A1 = LDS + REG;
  unsigned short* B0 = LDS + 2 * REG;
  unsigned short* B1 = LDS + 3 * REG;

  const int t = threadIdx.x;
  const int lane = t & 63, w = t >> 6;
  const int wm = w >> 1, wn = w & 1;
  const int lr = lane & 15, lg = lane >> 4;
  const int m0 = blockIdx.x * 128, n0 = blockIdx.y * 128;

  int sr[4], sc[4], sb[4];
#pragma unroll
  for (int i = 0; i < 4; ++i) {
    const int bo = (i * 256 + w * 64) * 16;
    const int o = bo + lane * 16;
    const int row = o >> 7, colb = o & 127;
    const int colp = colb ^ ((row & 3) << 4) ^ (((row >> 2) & 1) << 6);
    sr[i] = row; sc[i] = colp >> 1; sb[i] = bo >> 1;
  }

#define STAGE(e0, lA, lB)                                                           \
  do {                                                                              \
    _Pragma("unroll") for (int i = 0; i < 4; ++i) {                                 \
      gload_lds16(A + (size_t)(m0 + sr[i]) * DM + (e0) + sc[i], (lA) + sb[i]);      \
      gload_lds16(Bmat + (size_t)(n0 + sr[i]) * DM + (e0) + sc[i], (lB) + sb[i]);   \
    }                                                                               \
  } while (0)

  f32x4 acc[4][4];
#pragma unroll
  for (int m = 0; m < 4; ++m)
#pragma unroll
    for (int n = 0; n < 4; ++n) acc[m][n] = (f32x4){0.f, 0.f, 0.f, 0.f};

  const int xor6l = ((lr >> 2) & 1) << 6;
  const int xor45 = (lg << 4) ^ ((lr & 3) << 4);

#define COMPUTE(sAp, sBp)                                                           \
  do {                                                                              \
    _Pragma("unroll") for (int kk = 0; kk < 2; ++kk) {                              \
      const int coff = ((kk << 6) ^ xor6l) + xor45;                                 \
      short8 af[4], bf[4];                                                          \
      _Pragma("unroll") for (int m = 0; m < 4; ++m)                                 \
        af[m] = *(const short8*)((const char*)(sAp) + (wm * 64 + m * 16 + lr) * 128 + coff); \
      _Pragma("unroll") for (int n = 0; n < 4; ++n)                                 \
        bf[n] = *(const short8*)((const char*)(sBp) + (wn * 64 + n * 16 + lr) * 128 + coff); \
      _Pragma("unroll") for (int m = 0; m < 4; ++m)                                 \
        _Pragma("unroll") for (int n = 0; n < 4; ++n)                               \
          acc[m][n] = __builtin_amdgcn_mfma_f32_16x16x32_bf16(af[m], bf[n], acc[m][n], 0, 0, 0); \
    }                                                                               \
  } while (0)

  STAGE(0, A0, B0);
#pragma unroll 1
  for (int kt = 0; kt < 14; kt += 2) {
    STAGE((kt + 1) * 64, A1, B1);
    PIPE_WAIT8; PIPE_BAR;
    __builtin_amdgcn_s_setprio(1);
    COMPUTE(A0, B0);
    __builtin_amdgcn_s_setprio(0);
    PIPE_ENDBAR;
    STAGE((kt + 2) * 64, A0, B0);
    PIPE_WAIT8; PIPE_BAR;
    __builtin_amdgcn_s_setprio(1);
    COMPUTE(A1, B1);
    __builtin_amdgcn_s_setprio(0);
    PIPE_ENDBAR;
  }
  STAGE(15 * 64, A1, B1);
  PIPE_WAIT8; PIPE_BAR;
  __builtin_amdgcn_s_setprio(1);
  COMPUTE(A0, B0);
  __builtin_amdgcn_s_setprio(0);
  PIPE_ENDBAR;
  PIPE_WAIT0; PIPE_BAR;
  __builtin_amdgcn_s_setprio(1);
  COMPUTE(A1, B1);
  __builtin_amdgcn_s_setprio(0);

#undef STAGE
#undef COMPUTE

#pragma unroll
  for (int n = 0; n < 4; ++n) {
    const int gc = n0 + wn * 64 + n * 16 + lr;
    const float bv = bias[gc];
#pragma unroll
    for (int m = 0; m < 4; ++m) {
      const int gr0 = m0 + wm * 64 + m * 16 + lg * 4;
#pragma unroll
      for (int r = 0; r < 4; ++r)
        Of[(size_t)(gr0 + r) * DM + gc] = acc[m][n][r] + bv;
    }
  }
}

// ---------------------------------------------------------------------------
// Sliding-window attention v6: TWO q-tiles (64 rows) per warp sharing ONE
// pass over the union key window (10 chunks vs 2x9) -> K/V line traffic
// -45%.  Per chunk: stage V once, then TILE(A) / TILE(B) with warp-uniform
// skips (chunk 0 A-only, last chunk B-only for interior q-blocks).  Same
// swapped-QK^T static-max softmax math as measured-best v2.
// Grid 256 blocks x 4 warps = 1 wave/SIMD (latency/TLP proven non-binding
// in rounds 7/15; per-chunk ILP doubles).
// ---------------------------------------------------------------------------
__global__ __launch_bounds__(256) void attn(
    const unsigned short* __restrict__ Q,
    const unsigned short* __restrict__ Km,
    const unsigned short* __restrict__ Vm,
    unsigned short* __restrict__ AO)
{
  const int warp = threadIdx.x >> 6;
  const int l = threadIdx.x & 63;
  const int qw0 = (blockIdx.x * 4 + warp) * 64;   // 64 q-rows per warp
  const int hD = blockIdx.y * DH;
  const int q = l & 31;
  const int hi = l >> 5;
  const int l31 = l & 31;
  const int vkey = (l & 15) * 2;
  const int vd0 = (l >> 4) * 16;

  __shared__ __align__(16) unsigned short VtS[4][2][64 * 40];
  unsigned short* vt0 = &VtS[warp][0][0];
  unsigned short* vt1 = &VtS[warp][1][0];

  short8 qfA[4], qfB[4];
  {
    const unsigned short* qp = Q + (size_t)(qw0 + q) * DM + hD + hi * 8;
#pragma unroll
    for (int ks = 0; ks < 4; ++ks) qfA[ks] = *(const short8*)(qp + ks * 16);
    const unsigned short* qp2 = Q + (size_t)(qw0 + 32 + q) * DM + hD + hi * 8;
#pragma unroll
    for (int ks = 0; ks < 4; ++ks) qfB[ks] = *(const short8*)(qp2 + ks * 16);
  }

  f32x16 o0A{}, o1A{}, o0B{}, o1B{};
  float lsumA = 0.f, lsumB = 0.f;

  const int kb0 = (qw0 >= WIN) ? (qw0 - WIN) : 0;
  const int nch = (qw0 + 64 - kb0) >> 5;   // 2/4/6/8/10 — always even

  short8 kf1[4], vf1[4], kf2[4], vf2[4];

#define LOADKV(kb_, kf_, vf_)                                                    \
  do {                                                                           \
    const unsigned short* kp_ = Km + (size_t)((kb_) + l31) * DM + hD + hi * 8;   \
    (kf_)[0] = *(const short8*)kp_;                                              \
    (kf_)[1] = *(const short8*)(kp_ + 16);                                       \
    (kf_)[2] = *(const short8*)(kp_ + 32);                                       \
    (kf_)[3] = *(const short8*)(kp_ + 48);                                       \
    const unsigned short* vp_ = Vm + (size_t)((kb_) + vkey) * DM + hD + vd0;     \
    (vf_)[0] = *(const short8*)vp_;                                              \
    (vf_)[1] = *(const short8*)(vp_ + 8);                                        \
    (vf_)[2] = *(const short8*)(vp_ + DM);                                       \
    (vf_)[3] = *(const short8*)(vp_ + DM + 8);                                   \
  } while (0)

// One 32x32 q-tile against the current 32-key chunk.
#define TILE(qb_, qf_, o0_, o1_, ls_, kbv_, kf_, vt_)                           \
  do {                                                                          \
    f32x16 s{};                                                                 \
    _Pragma("unroll") for (int ks = 0; ks < 4; ++ks)                            \
      s = __builtin_amdgcn_mfma_f32_32x32x16_bf16((kf_)[ks], (qf_)[ks], s, 0, 0, 0); \
    float p[16];                                                                \
    const bool isEdge = ((kbv_) >= (qb_)) || ((kbv_) + WIN - 32 < (qb_));       \
    if (isEdge) {                                                               \
      _Pragma("unroll") for (int r = 0; r < 16; ++r) {                          \
        const int key = (kbv_) + (r & 3) + 8 * (r >> 2) + 4 * hi;               \
        const int qg = (qb_) + q;                                               \
        const bool valid = (key <= qg) && (qg - key < WIN);                     \
        p[r] = valid ? __expf(s[r] * 0.125f) : 0.f;                             \
        (ls_) += p[r];                                                          \
      }                                                                         \
    } else {                                                                    \
      _Pragma("unroll") for (int r = 0; r < 16; ++r) {                          \
        p[r] = __expf(s[r] * 0.125f);                                           \
        (ls_) += p[r];                                                          \
      }                                                                         \
    }                                                                           \
    unsigned int u[8];                                                          \
    _Pragma("unroll") for (int t2 = 0; t2 < 4; ++t2) {                          \
      __hip_bfloat162 h0_ = __float22bfloat162_rn(make_float2(p[4 * t2], p[4 * t2 + 1])); \
      __hip_bfloat162 h1_ = __float22bfloat162_rn(make_float2(p[4 * t2 + 2], p[4 * t2 + 3])); \
      u[2 * t2]     = *(unsigned int*)&h0_;                                     \
      u[2 * t2 + 1] = *(unsigned int*)&h1_;                                     \
    }                                                                           \
    const unsigned int sd0 = hi ? u[0] : u[2], sd1 = hi ? u[1] : u[3];          \
    const unsigned int rc0 = __shfl_xor(sd0, 32, 64), rc1 = __shfl_xor(sd1, 32, 64); \
    const unsigned int sd2 = hi ? u[4] : u[6], sd3 = hi ? u[5] : u[7];          \
    const unsigned int rc2 = __shfl_xor(sd2, 32, 64), rc3 = __shfl_xor(sd3, 32, 64); \
    i32x4 pw0, pw1;                                                             \
    pw0[0] = hi ? rc0 : u[0]; pw0[1] = hi ? rc1 : u[1];                         \
    pw0[2] = hi ? u[2] : rc0; pw0[3] = hi ? u[3] : rc1;                         \
    pw1[0] = hi ? rc2 : u[4]; pw1[1] = hi ? rc3 : u[5];                         \
    pw1[2] = hi ? u[6] : rc2; pw1[3] = hi ? u[7] : rc3;                         \
    const short8 pf0 = *(const short8*)&pw0;                                    \
    const short8 pf1 = *(const short8*)&pw1;                                    \
    const short8 a00 = *(const short8*)((vt_) + l31 * 40 + hi * 8);             \
    const short8 a01 = *(const short8*)((vt_) + l31 * 40 + 16 + hi * 8);        \
    const short8 a10 = *(const short8*)((vt_) + (32 + l31) * 40 + hi * 8);      \
    const short8 a11 = *(const short8*)((vt_) + (32 + l31) * 40 + 16 + hi * 8); \
    (o0_) = __builtin_amdgcn_mfma_f32_32x32x16_bf16(a00, pf0, (o0_), 0, 0, 0);  \
    (o0_) = __builtin_amdgcn_mfma_f32_32x32x16_bf16(a01, pf1, (o0_), 0, 0, 0);  \
    (o1_) = __builtin_amdgcn_mfma_f32_32x32x16_bf16(a10, pf0, (o1_), 0, 0, 0);  \
    (o1_) = __builtin_amdgcn_mfma_f32_32x32x16_bf16(a11, pf1, (o1_), 0, 0, 0);  \
  } while (0)

// Per chunk: stage V once; run both q-tiles with warp-uniform skips.
#define CHUNK(kb_, kf_, vf_, vt_)                                               \
  do {                                                                          \
    const int kbC = (kb_);                                                      \
    _Pragma("unroll") for (int j = 0; j < 16; ++j) {                            \
      unsigned int wv = (unsigned int)(unsigned short)(vf_)[j >> 3][j & 7]      \
          | ((unsigned int)(unsigned short)(vf_)[2 + (j >> 3)][j & 7] << 16);   \
      *(unsigned int*)((vt_) + (vd0 + j) * 40 + vkey) = wv;                     \
    }                                                                           \
    if (kbC < qw0 + 32)                                                         \
      TILE(qw0, qfA, o0A, o1A, lsumA, kbC, kf_, vt_);                           \
    if (kbC >= qw0 - 254)                                                       \
      TILE(qw0 + 32, qfB, o0B, o1B, lsumB, kbC, kf_, vt_);                      \
  } while (0)

  LOADKV(kb0, kf1, vf1);
  int c = 0;
#pragma unroll 1
  for (; c + 2 <= nch; c += 2) {
    const int kb = kb0 + c * 32;
    LOADKV(kb + 32, kf2, vf2);
    CHUNK(kb, kf1, vf1, vt0);
    if (c + 2 < nch) LOADKV(kb + 64, kf1, vf1);
    CHUNK(kb + 32, kf2, vf2, vt1);
  }
  if (c < nch) CHUNK(kb0 + c * 32, kf1, vf1, vt0);   // dead (nch even); kept for safety

#undef LOADKV
#undef TILE
#undef CHUNK

  lsumA += __shfl_xor(lsumA, 32, 64);
  lsumB += __shfl_xor(lsumB, 32, 64);
  const float invA = 1.f / lsumA;
  const float invB = 1.f / lsumB;
  unsigned short* aopA = AO + (size_t)(qw0 + q) * DM + hD;
  unsigned short* aopB = AO + (size_t)(qw0 + 32 + q) * DM + hD;
#pragma unroll
  for (int t2 = 0; t2 < 4; ++t2) {
    __hip_bfloat162 s0 = __float22bfloat162_rn(make_float2(o0A[4*t2] * invA, o0A[4*t2+1] * invA));
    __hip_bfloat162 s1 = __float22bfloat162_rn(make_float2(o0A[4*t2+2] * invA, o0A[4*t2+3] * invA));
    uint2 st; st.x = *(unsigned int*)&s0; st.y = *(unsigned int*)&s1;
    *(uint2*)(aopA + 8 * t2 + 4 * hi) = st;
    __hip_bfloat162 s2 = __float22bfloat162_rn(make_float2(o1A[4*t2] * invA, o1A[4*t2+1] * invA));
    __hip_bfloat162 s3 = __float22bfloat162_rn(make_float2(o1A[4*t2+2] * invA, o1A[4*t2+3] * invA));
    uint2 st2; st2.x = *(unsigned int*)&s2; st2.y = *(unsigned int*)&s3;
    *(uint2*)(aopA + 32 + 8 * t2 + 4 * hi) = st2;
    __hip_bfloat162 s4 = __float22bfloat162_rn(make_float2(o0B[4*t2] * invB, o0B[4*t2+1] * invB));
    __hip_bfloat162 s5 = __float22bfloat162_rn(make_float2(o0B[4*t2+2] * invB, o0B[4*t2+3] * invB));
    uint2 st3; st3.x = *(unsigned int*)&s4; st3.y = *(unsigned int*)&s5;
    *(uint2*)(aopB + 8 * t2 + 4 * hi) = st3;
    __hip_bfloat162 s6 = __float22bfloat162_rn(make_float2(o1B[4*t2] * invB, o1B[4*t2+1] * invB));
    __hip_bfloat162 s7 = __float22bfloat162_rn(make_float2(o1B[4*t2+2] * invB, o1B[4*t2+3] * invB));
    uint2 st4; st4.x = *(unsigned int*)&s6; st4.y = *(unsigned int*)&s7;
    *(uint2*)(aopB + 32 + 8 * t2 + 4 * hi) = st4;
  }
}

// ---------------------------------------------------------------------------
extern "C" void kernel_launch(void* const* d_in, const int* in_sizes, int n_in,
                              void* d_out, int out_size, void* d_ws, size_t ws_size,
                              hipStream_t stream) {
  const float* x  = (const float*)d_in[0];
  const float* qw = (const float*)d_in[1];
  const float* qb = (const float*)d_in[2];
  const float* kw = (const float*)d_in[3];
  const float* kb = (const float*)d_in[4];
  const float* vw = (const float*)d_in[5];
  const float* vb = (const float*)d_in[6];
  const float* ow = (const float*)d_in[7];
  const float* ob = (const float*)d_in[8];

  const size_t SD = (size_t)S_LEN * DM;
  unsigned short* Qb  = (unsigned short*)d_ws;
  unsigned short* Kb  = Qb + SD;
  unsigned short* Vb  = Kb + SD;
  unsigned short* AOb = Vb + SD;
  unsigned short* Xb  = AOb + SD;
  unsigned short* Wcv = Xb + SD;

  cvt_all<<<dim3(2048, 5), 256, 0, stream>>>(x, qw, kw, vw, ow, Xb, Wcv);
  gemm_qkv_fused<<<dim3(16, 16), 512, 0, stream>>>(Xb, Wcv, qb, kb, vb, Qb);
  attn<<<dim3(S_LEN / 256, NH), 256, 0, stream>>>(Qb, Kb, Vb, AOb);
  gemm_out<<<dim3(32, 8), 256, 0, stream>>>(AOb, Wcv + (size_t)3 * DM * DM, ob, (float*)d_out);
}

// Round 20
// 79.524 us; speedup vs baseline: 1.1126x; 1.0004x over previous
//
#include <hip/hip_runtime.h>
#include <hip/hip_bf16.h>

typedef __attribute__((ext_vector_type(4))) float f32x4;
typedef __attribute__((ext_vector_type(16))) float f32x16;
typedef __attribute__((ext_vector_type(8))) short short8;
typedef __attribute__((ext_vector_type(4))) int i32x4;

#define S_LEN 4096
#define DM    1024
#define NH    16
#define DH    64
#define WIN   256

__device__ inline unsigned short f2b(float f) {
  unsigned int x = __float_as_uint(f);
  unsigned int r = (x + 0x7fffu + ((x >> 16) & 1u)) >> 16;
  return (unsigned short)r;
}

__device__ inline void gload_lds16(const void* g, void* l) {
  __builtin_amdgcn_global_load_lds(
      (const __attribute__((address_space(1))) void*)g,
      (__attribute__((address_space(3))) void*)l, 16, 0, 0);
}

// ---------------------------------------------------------------------------
// Convert X and the 4 weight matrices f32 -> bf16.
// ---------------------------------------------------------------------------
__global__ __launch_bounds__(256) void cvt_all(
    const float* __restrict__ x,
    const float* __restrict__ qw, const float* __restrict__ kw,
    const float* __restrict__ vw, const float* __restrict__ ow,
    unsigned short* __restrict__ Xb, unsigned short* __restrict__ Wb)
{
  const int y = blockIdx.y;
  const float* src;
  unsigned short* dst;
  int n8;
  if (y == 0) { src = x; dst = Xb; n8 = (S_LEN * DM) / 8; }
  else {
    src = (y == 1) ? qw : (y == 2) ? kw : (y == 3) ? vw : ow;
    dst = Wb + (size_t)(y - 1) * DM * DM;
    n8 = (DM * DM) / 8;
  }
  const int i = blockIdx.x * 256 + threadIdx.x;
  if (i >= n8) return;
  const float4* s4 = (const float4*)src + (size_t)i * 2;
  float4 a = s4[0], b = s4[1];
  short8 v;
  v[0] = f2b(a.x); v[1] = f2b(a.y); v[2] = f2b(a.z); v[3] = f2b(a.w);
  v[4] = f2b(b.x); v[5] = f2b(b.y); v[6] = f2b(b.z); v[7] = f2b(b.w);
  *(short8*)(dst + (size_t)i * 8) = v;
}

#define PIPE_WAIT8  asm volatile("s_waitcnt vmcnt(8)" ::: "memory")
#define PIPE_WAIT7  asm volatile("s_waitcnt vmcnt(7)" ::: "memory")
#define PIPE_WAIT0  asm volatile("s_waitcnt vmcnt(0)" ::: "memory")
#define PIPE_BAR    do { __builtin_amdgcn_s_barrier(); __builtin_amdgcn_sched_barrier(0); } while (0)
#define PIPE_ENDBAR do { __builtin_amdgcn_sched_barrier(0); __builtin_amdgcn_s_barrier(); \
                         __builtin_amdgcn_sched_barrier(0); } while (0)

// ---------------------------------------------------------------------------
// Fused QKV GEMM (4096x3072), BM=256 BN=192, 256 blocks = 1/CU, 2-phase
// counted-vmcnt pipeline.  NEW: XCD panel-locality swizzle — each XCD owns
// an 8Mx4N tile region, so its 4 B-panels (3MB) fit its private L2 and 7/8
// of B re-reads (and half of A re-reads) move from L3 to L2.
// Mapping (bijective over 256 blocks): xcd=bid&7, s=bid>>3,
//   m=(s&7)+8*(xcd&1), n=(s>>3)+4*(xcd>>1).
// ---------------------------------------------------------------------------
__global__ __launch_bounds__(512, 1) void gemm_qkv_fused(
    const unsigned short* __restrict__ A,    // Xb [4096][1024]
    const unsigned short* __restrict__ W,    // Wcv rows 0..3071 = q,k,v
    const float* __restrict__ bq, const float* __restrict__ bk, const float* __restrict__ bv,
    unsigned short* __restrict__ Qb)         // K at +SD, V at +2SD
{
  constexpr int BM = 256, BN = 192;
  constexpr int REGA = BM * 64;
  constexpr int BUF = REGA + BN * 64;
  __shared__ __align__(16) unsigned short LDS[2 * BUF];
  unsigned short* A0 = LDS;
  unsigned short* B0 = LDS + REGA;
  unsigned short* A1 = LDS + BUF;
  unsigned short* B1 = LDS + BUF + REGA;

  const int bid = blockIdx.x;
  const int xcd = bid & 7;
  const int s = bid >> 3;                      // 0..31
  const int mt = (s & 7) + 8 * (xcd & 1);      // 0..15
  const int nt = (s >> 3) + 4 * (xcd >> 1);    // 0..15
  const int m0 = mt * BM, n0 = nt * BN;

  const int t = threadIdx.x;
  const int lane = t & 63, w = t >> 6;
  const int wm = w >> 2, wn = w & 3;
  const int lr = lane & 15, lg = lane >> 4;

  int sr[4], sc[4], sb[4];
#pragma unroll
  for (int i = 0; i < 4; ++i) {
    const int bo = (i * 512 + w * 64) * 16;
    const int o = bo + lane * 16;
    const int row = o >> 7, colb = o & 127;
    const int colp = colb ^ ((row & 3) << 4) ^ (((row >> 2) & 1) << 6);
    sr[i] = row; sc[i] = colp >> 1; sb[i] = bo >> 1;
  }

#define STAGE(e0, lA, lB)                                                           \
  do {                                                                              \
    _Pragma("unroll") for (int i = 0; i < 4; ++i)                                   \
      gload_lds16(A + (size_t)(m0 + sr[i]) * DM + (e0) + sc[i], (lA) + sb[i]);      \
    _Pragma("unroll") for (int i = 0; i < 3; ++i)                                   \
      gload_lds16(W + (size_t)(n0 + sr[i]) * DM + (e0) + sc[i], (lB) + sb[i]);      \
  } while (0)

  f32x4 acc[8][3];
#pragma unroll
  for (int m = 0; m < 8; ++m)
#pragma unroll
    for (int n = 0; n < 3; ++n) acc[m][n] = (f32x4){0.f, 0.f, 0.f, 0.f};

  const int xor6l = ((lr >> 2) & 1) << 6;
  const int xor45 = (lg << 4) ^ ((lr & 3) << 4);

#define COMPUTE(sAp, sBp)                                                           \
  do {                                                                              \
    _Pragma("unroll") for (int kk = 0; kk < 2; ++kk) {                              \
      const int coff = ((kk << 6) ^ xor6l) + xor45;                                 \
      short8 af[8], bf[3];                                                          \
      _Pragma("unroll") for (int m = 0; m < 8; ++m)                                 \
        af[m] = *(const short8*)((const char*)(sAp) + (wm * 128 + m * 16 + lr) * 128 + coff); \
      _Pragma("unroll") for (int n = 0; n < 3; ++n)                                 \
        bf[n] = *(const short8*)((const char*)(sBp) + (wn * 48 + n * 16 + lr) * 128 + coff); \
      _Pragma("unroll") for (int m = 0; m < 8; ++m)                                 \
        _Pragma("unroll") for (int n = 0; n < 3; ++n)                               \
          acc[m][n] = __builtin_amdgcn_mfma_f32_16x16x32_bf16(af[m], bf[n], acc[m][n], 0, 0, 0); \
    }                                                                               \
  } while (0)

  STAGE(0, A0, B0);
#pragma unroll 1
  for (int kt = 0; kt < 14; kt += 2) {
    STAGE((kt + 1) * 64, A1, B1);
    PIPE_WAIT7; PIPE_BAR;
    __builtin_amdgcn_s_setprio(1);
    COMPUTE(A0, B0);
    __builtin_amdgcn_s_setprio(0);
    PIPE_ENDBAR;
    STAGE((kt + 2) * 64, A0, B0);
    PIPE_WAIT7; PIPE_BAR;
    __builtin_amdgcn_s_setprio(1);
    COMPUTE(A1, B1);
    __builtin_amdgcn_s_setprio(0);
    PIPE_ENDBAR;
  }
  STAGE(15 * 64, A1, B1);
  PIPE_WAIT7; PIPE_BAR;
  __builtin_amdgcn_s_setprio(1);
  COMPUTE(A0, B0);
  __builtin_amdgcn_s_setprio(0);
  PIPE_ENDBAR;
  PIPE_WAIT0; PIPE_BAR;
  __builtin_amdgcn_s_setprio(1);
  COMPUTE(A1, B1);
  __builtin_amdgcn_s_setprio(0);

#undef STAGE
#undef COMPUTE

#pragma unroll
  for (int n = 0; n < 3; ++n) {
    const int gc = n0 + wn * 48 + n * 16 + lr;
    const int slice = gc >> 10, col = gc & 1023;
    const float* bp = (slice == 0) ? bq : (slice == 1) ? bk : bv;
    const float bv_ = bp[col];
    unsigned short* Obase = Qb + (size_t)slice * ((size_t)S_LEN * DM);
#pragma unroll
    for (int m = 0; m < 8; ++m) {
      const int gr0 = m0 + wm * 128 + m * 16 + lg * 4;
#pragma unroll
      for (int r = 0; r < 4; ++r)
        Obase[(size_t)(gr0 + r) * DM + col] = f2b(acc[m][n][r] + bv_);
    }
  }
}

// ---------------------------------------------------------------------------
// 128x128 2-phase pipelined GEMM for the output projection (round-10 form).
// ---------------------------------------------------------------------------
__global__ __launch_bounds__(256, 1) void gemm_out(
    const unsigned short* __restrict__ A,
    const unsigned short* __restrict__ Bmat,
    const float* __restrict__ bias,
    float* __restrict__ Of)
{
  constexpr int REG = 128 * 64;
  __shared__ __align__(16) unsigned short LDS[4 * REG];
  unsigned short* A0 = LDS;
  unsigned short* A1 = LDS + REG;
  unsigned short* B0 = LDS + 2 * REG;
  unsigned short* B1 = LDS + 3 * REG;

  const int t = threadIdx.x;
  const int lane = t & 63, w = t >> 6;
  const int wm = w >> 1, wn = w & 1;
  const int lr = lane & 15, lg = lane >> 4;
  const int m0 = blockIdx.x * 128, n0 = blockIdx.y * 128;

  int sr[4], sc[4], sb[4];
#pragma unroll
  for (int i = 0; i < 4; ++i) {
    const int bo = (i * 256 + w * 64) * 16;
    const int o = bo + lane * 16;
    const int row = o >> 7, colb = o & 127;
    const int colp = colb ^ ((row & 3) << 4) ^ (((row >> 2) & 1) << 6);
    sr[i] = row; sc[i] = colp >> 1; sb[i] = bo >> 1;
  }

#define STAGE(e0, lA, lB)                                                           \
  do {                                                                              \
    _Pragma("unroll") for (int i = 0; i < 4; ++i) {                                 \
      gload_lds16(A + (size_t)(m0 + sr[i]) * DM + (e0) + sc[i], (lA) + sb[i]);      \
      gload_lds16(Bmat + (size_t)(n0 + sr[i]) * DM + (e0) + sc[i], (lB) + sb[i]);   \
    }                                                                               \
  } while (0)

  f32x4 acc[4][4];
#pragma unroll
  for (int m = 0; m < 4; ++m)
#pragma unroll
    for (int n = 0; n < 4; ++n) acc[m][n] = (f32x4){0.f, 0.f, 0.f, 0.f};

  const int xor6l = ((lr >> 2) & 1) << 6;
  const int xor45 = (lg << 4) ^ ((lr & 3) << 4);

#define COMPUTE(sAp, sBp)                                                           \
  do {                                                                              \
    _Pragma("unroll") for (int kk = 0; kk < 2; ++kk) {                              \
      const int coff = ((kk << 6) ^ xor6l) + xor45;                                 \
      short8 af[4], bf[4];                                                          \
      _Pragma("unroll") for (int m = 0; m < 4; ++m)                                 \
        af[m] = *(const short8*)((const char*)(sAp) + (wm * 64 + m * 16 + lr) * 128 + coff); \
      _Pragma("unroll") for (int n = 0; n < 4; ++n)                                 \
        bf[n] = *(const short8*)((const char*)(sBp) + (wn * 64 + n * 16 + lr) * 128 + coff); \
      _Pragma("unroll") for (int m = 0; m < 4; ++m)                                 \
        _Pragma("unroll") for (int n = 0; n < 4; ++n)                               \
          acc[m][n] = __builtin_amdgcn_mfma_f32_16x16x32_bf16(af[m], bf[n], acc[m][n], 0, 0, 0); \
    }                                                                               \
  } while (0)

  STAGE(0, A0, B0);
#pragma unroll 1
  for (int kt = 0; kt < 14; kt += 2) {
    STAGE((kt + 1) * 64, A1, B1);
    PIPE_WAIT8; PIPE_BAR;
    __builtin_amdgcn_s_setprio(1);
    COMPUTE(A0, B0);
    __builtin_amdgcn_s_setprio(0);
    PIPE_ENDBAR;
    STAGE((kt + 2) * 64, A0, B0);
    PIPE_WAIT8; PIPE_BAR;
    __builtin_amdgcn_s_setprio(1);
    COMPUTE(A1, B1);
    __builtin_amdgcn_s_setprio(0);
    PIPE_ENDBAR;
  }
  STAGE(15 * 64, A1, B1);
  PIPE_WAIT8; PIPE_BAR;
  __builtin_amdgcn_s_setprio(1);
  COMPUTE(A0, B0);
  __builtin_amdgcn_s_setprio(0);
  PIPE_ENDBAR;
  PIPE_WAIT0; PIPE_BAR;
  __builtin_amdgcn_s_setprio(1);
  COMPUTE(A1, B1);
  __builtin_amdgcn_s_setprio(0);

#undef STAGE
#undef COMPUTE

#pragma unroll
  for (int n = 0; n < 4; ++n) {
    const int gc = n0 + wn * 64 + n * 16 + lr;
    const float bv = bias[gc];
#pragma unroll
    for (int m = 0; m < 4; ++m) {
      const int gr0 = m0 + wm * 64 + m * 16 + lg * 4;
#pragma unroll
      for (int r = 0; r < 4; ++r)
        Of[(size_t)(gr0 + r) * DM + gc] = acc[m][n][r] + bv;
    }
  }
}

// ---------------------------------------------------------------------------
// Sliding-window attention v6 (round-19 measured-best): two q-tiles per warp
// sharing one pass over the union key window; swapped QK^T, static-max
// softmax, zero barriers, per-warp double-buffered V^T LDS.
// ---------------------------------------------------------------------------
__global__ __launch_bounds__(256) void attn(
    const unsigned short* __restrict__ Q,
    const unsigned short* __restrict__ Km,
    const unsigned short* __restrict__ Vm,
    unsigned short* __restrict__ AO)
{
  const int warp = threadIdx.x >> 6;
  const int l = threadIdx.x & 63;
  const int qw0 = (blockIdx.x * 4 + warp) * 64;
  const int hD = blockIdx.y * DH;
  const int q = l & 31;
  const int hi = l >> 5;
  const int l31 = l & 31;
  const int vkey = (l & 15) * 2;
  const int vd0 = (l >> 4) * 16;

  __shared__ __align__(16) unsigned short VtS[4][2][64 * 40];
  unsigned short* vt0 = &VtS[warp][0][0];
  unsigned short* vt1 = &VtS[warp][1][0];

  short8 qfA[4], qfB[4];
  {
    const unsigned short* qp = Q + (size_t)(qw0 + q) * DM + hD + hi * 8;
#pragma unroll
    for (int ks = 0; ks < 4; ++ks) qfA[ks] = *(const short8*)(qp + ks * 16);
    const unsigned short* qp2 = Q + (size_t)(qw0 + 32 + q) * DM + hD + hi * 8;
#pragma unroll
    for (int ks = 0; ks < 4; ++ks) qfB[ks] = *(const short8*)(qp2 + ks * 16);
  }

  f32x16 o0A{}, o1A{}, o0B{}, o1B{};
  float lsumA = 0.f, lsumB = 0.f;

  const int kb0 = (qw0 >= WIN) ? (qw0 - WIN) : 0;
  const int nch = (qw0 + 64 - kb0) >> 5;

  short8 kf1[4], vf1[4], kf2[4], vf2[4];

#define LOADKV(kb_, kf_, vf_)                                                    \
  do {                                                                           \
    const unsigned short* kp_ = Km + (size_t)((kb_) + l31) * DM + hD + hi * 8;   \
    (kf_)[0] = *(const short8*)kp_;                                              \
    (kf_)[1] = *(const short8*)(kp_ + 16);                                       \
    (kf_)[2] = *(const short8*)(kp_ + 32);                                       \
    (kf_)[3] = *(const short8*)(kp_ + 48);                                       \
    const unsigned short* vp_ = Vm + (size_t)((kb_) + vkey) * DM + hD + vd0;     \
    (vf_)[0] = *(const short8*)vp_;                                              \
    (vf_)[1] = *(const short8*)(vp_ + 8);                                        \
    (vf_)[2] = *(const short8*)(vp_ + DM);                                       \
    (vf_)[3] = *(const short8*)(vp_ + DM + 8);                                   \
  } while (0)

#define TILE(qb_, qf_, o0_, o1_, ls_, kbv_, kf_, vt_)                           \
  do {                                                                          \
    f32x16 s{};                                                                 \
    _Pragma("unroll") for (int ks = 0; ks < 4; ++ks)                            \
      s = __builtin_amdgcn_mfma_f32_32x32x16_bf16((kf_)[ks], (qf_)[ks], s, 0, 0, 0); \
    float p[16];                                                                \
    const bool isEdge = ((kbv_) >= (qb_)) || ((kbv_) + WIN - 32 < (qb_));       \
    if (isEdge) {                                                               \
      _Pragma("unroll") for (int r = 0; r < 16; ++r) {                          \
        const int key = (kbv_) + (r & 3) + 8 * (r >> 2) + 4 * hi;               \
        const int qg = (qb_) + q;                                               \
        const bool valid = (key <= qg) && (qg - key < WIN);                     \
        p[r] = valid ? __expf(s[r] * 0.125f) : 0.f;                             \
        (ls_) += p[r];                                                          \
      }                                                                         \
    } else {                                                                    \
      _Pragma("unroll") for (int r = 0; r < 16; ++r) {                          \
        p[r] = __expf(s[r] * 0.125f);                                           \
        (ls_) += p[r];                                                          \
      }                                                                         \
    }                                                                           \
    unsigned int u[8];                                                          \
    _Pragma("unroll") for (int t2 = 0; t2 < 4; ++t2) {                          \
      __hip_bfloat162 h0_ = __float22bfloat162_rn(make_float2(p[4 * t2], p[4 * t2 + 1])); \
      __hip_bfloat162 h1_ = __float22bfloat162_rn(make_float2(p[4 * t2 + 2], p[4 * t2 + 3])); \
      u[2 * t2]     = *(unsigned int*)&h0_;                                     \
      u[2 * t2 + 1] = *(unsigned int*)&h1_;                                     \
    }                                                                           \
    const unsigned int sd0 = hi ? u[0] : u[2], sd1 = hi ? u[1] : u[3];          \
    const unsigned int rc0 = __shfl_xor(sd0, 32, 64), rc1 = __shfl_xor(sd1, 32, 64); \
    const unsigned int sd2 = hi ? u[4] : u[6], sd3 = hi ? u[5] : u[7];          \
    const unsigned int rc2 = __shfl_xor(sd2, 32, 64), rc3 = __shfl_xor(sd3, 32, 64); \
    i32x4 pw0, pw1;                                                             \
    pw0[0] = hi ? rc0 : u[0]; pw0[1] = hi ? rc1 : u[1];                         \
    pw0[2] = hi ? u[2] : rc0; pw0[3] = hi ? u[3] : rc1;                         \
    pw1[0] = hi ? rc2 : u[4]; pw1[1] = hi ? rc3 : u[5];                         \
    pw1[2] = hi ? u[6] : rc2; pw1[3] = hi ? u[7] : rc3;                         \
    const short8 pf0 = *(const short8*)&pw0;                                    \
    const short8 pf1 = *(const short8*)&pw1;                                    \
    const short8 a00 = *(const short8*)((vt_) + l31 * 40 + hi * 8);             \
    const short8 a01 = *(const short8*)((vt_) + l31 * 40 + 16 + hi * 8);        \
    const short8 a10 = *(const short8*)((vt_) + (32 + l31) * 40 + hi * 8);      \
    const short8 a11 = *(const short8*)((vt_) + (32 + l31) * 40 + 16 + hi * 8); \
    (o0_) = __builtin_amdgcn_mfma_f32_32x32x16_bf16(a00, pf0, (o0_), 0, 0, 0);  \
    (o0_) = __builtin_amdgcn_mfma_f32_32x32x16_bf16(a01, pf1, (o0_), 0, 0, 0);  \
    (o1_) = __builtin_amdgcn_mfma_f32_32x32x16_bf16(a10, pf0, (o1_), 0, 0, 0);  \
    (o1_) = __builtin_amdgcn_mfma_f32_32x32x16_bf16(a11, pf1, (o1_), 0, 0, 0);  \
  } while (0)

#define CHUNK(kb_, kf_, vf_, vt_)                                               \
  do {                                                                          \
    const int kbC = (kb_);                                                      \
    _Pragma("unroll") for (int j = 0; j < 16; ++j) {                            \
      unsigned int wv = (unsigned int)(unsigned short)(vf_)[j >> 3][j & 7]      \
          | ((unsigned int)(unsigned short)(vf_)[2 + (j >> 3)][j & 7] << 16);   \
      *(unsigned int*)((vt_) + (vd0 + j) * 40 + vkey) = wv;                     \
    }                                                                           \
    if (kbC < qw0 + 32)                                                         \
      TILE(qw0, qfA, o0A, o1A, lsumA, kbC, kf_, vt_);                           \
    if (kbC >= qw0 - 254)                                                       \
      TILE(qw0 + 32, qfB, o0B, o1B, lsumB, kbC, kf_, vt_);                      \
  } while (0)

  LOADKV(kb0, kf1, vf1);
  int c = 0;
#pragma unroll 1
  for (; c + 2 <= nch; c += 2) {
    const int kb = kb0 + c * 32;
    LOADKV(kb + 32, kf2, vf2);
    CHUNK(kb, kf1, vf1, vt0);
    if (c + 2 < nch) LOADKV(kb + 64, kf1, vf1);
    CHUNK(kb + 32, kf2, vf2, vt1);
  }
  if (c < nch) CHUNK(kb0 + c * 32, kf1, vf1, vt0);

#undef LOADKV
#undef TILE
#undef CHUNK

  lsumA += __shfl_xor(lsumA, 32, 64);
  lsumB += __shfl_xor(lsumB, 32, 64);
  const float invA = 1.f / lsumA;
  const float invB = 1.f / lsumB;
  unsigned short* aopA = AO + (size_t)(qw0 + q) * DM + hD;
  unsigned short* aopB = AO + (size_t)(qw0 + 32 + q) * DM + hD;
#pragma unroll
  for (int t2 = 0; t2 < 4; ++t2) {
    __hip_bfloat162 s0 = __float22bfloat162_rn(make_float2(o0A[4*t2] * invA, o0A[4*t2+1] * invA));
    __hip_bfloat162 s1 = __float22bfloat162_rn(make_float2(o0A[4*t2+2] * invA, o0A[4*t2+3] * invA));
    uint2 st; st.x = *(unsigned int*)&s0; st.y = *(unsigned int*)&s1;
    *(uint2*)(aopA + 8 * t2 + 4 * hi) = st;
    __hip_bfloat162 s2 = __float22bfloat162_rn(make_float2(o1A[4*t2] * invA, o1A[4*t2+1] * invA));
    __hip_bfloat162 s3 = __float22bfloat162_rn(make_float2(o1A[4*t2+2] * invA, o1A[4*t2+3] * invA));
    uint2 st2; st2.x = *(unsigned int*)&s2; st2.y = *(unsigned int*)&s3;
    *(uint2*)(aopA + 32 + 8 * t2 + 4 * hi) = st2;
    __hip_bfloat162 s4 = __float22bfloat162_rn(make_float2(o0B[4*t2] * invB, o0B[4*t2+1] * invB));
    __hip_bfloat162 s5 = __float22bfloat162_rn(make_float2(o0B[4*t2+2] * invB, o0B[4*t2+3] * invB));
    uint2 st3; st3.x = *(unsigned int*)&s4; st3.y = *(unsigned int*)&s5;
    *(uint2*)(aopB + 8 * t2 + 4 * hi) = st3;
    __hip_bfloat162 s6 = __float22bfloat162_rn(make_float2(o1B[4*t2] * invB, o1B[4*t2+1] * invB));
    __hip_bfloat162 s7 = __float22bfloat162_rn(make_float2(o1B[4*t2+2] * invB, o1B[4*t2+3] * invB));
    uint2 st4; st4.x = *(unsigned int*)&s6; st4.y = *(unsigned int*)&s7;
    *(uint2*)(aopB + 32 + 8 * t2 + 4 * hi) = st4;
  }
}

// ---------------------------------------------------------------------------
extern "C" void kernel_launch(void* const* d_in, const int* in_sizes, int n_in,
                              void* d_out, int out_size, void* d_ws, size_t ws_size,
                              hipStream_t stream) {
  const float* x  = (const float*)d_in[0];
  const float* qw = (const float*)d_in[1];
  const float* qb = (const float*)d_in[2];
  const float* kw = (const float*)d_in[3];
  const float* kb = (const float*)d_in[4];
  const float* vw = (const float*)d_in[5];
  const float* vb = (const float*)d_in[6];
  const float* ow = (const float*)d_in[7];
  const float* ob = (const float*)d_in[8];

  const size_t SD = (size_t)S_LEN * DM;
  unsigned short* Qb  = (unsigned short*)d_ws;
  unsigned short* Kb  = Qb + SD;
  unsigned short* Vb  = Kb + SD;
  unsigned short* AOb = Vb + SD;
  unsigned short* Xb  = AOb + SD;
  unsigned short* Wcv = Xb + SD;

  cvt_all<<<dim3(2048, 5), 256, 0, stream>>>(x, qw, kw, vw, ow, Xb, Wcv);
  gemm_qkv_fused<<<dim3(256), 512, 0, stream>>>(Xb, Wcv, qb, kb, vb, Qb);
  attn<<<dim3(S_LEN / 256, NH), 256, 0, stream>>>(Qb, Kb, Vb, AOb);
  gemm_out<<<dim3(32, 8), 256, 0, stream>>>(AOb, Wcv + (size_t)3 * DM * DM, ob, (float*)d_out);
}